// Round 6
// baseline (896.747 us; speedup 1.0000x reference)
//
#include <hip/hip_runtime.h>

#define NN 50000
#define EE 600000
#define DD 128
#define HH 256
#define LL 6
#define NB 49   // ceil(NN/1024)

typedef _Float16 f16x8 __attribute__((ext_vector_type(8)));
typedef float f32x4 __attribute__((ext_vector_type(4)));

__device__ __forceinline__ float bf2f(unsigned short u){
  unsigned int x = ((unsigned int)u) << 16; float f; __builtin_memcpy(&f, &x, 4); return f;
}
__device__ __forceinline__ unsigned short f2bf(float f){
  unsigned int x; __builtin_memcpy(&x, &f, 4);
  unsigned int lsb = (x >> 16) & 1u; x += 0x7fffu + lsb; return (unsigned short)(x >> 16);
}
__device__ __forceinline__ float wave_sum(float v){
  #pragma unroll
  for (int off = 32; off >= 1; off >>= 1) v += __shfl_xor(v, off, 64);
  return v;
}
__device__ __forceinline__ unsigned short f2h(float f){
  _Float16 h = (_Float16)f; unsigned short u; __builtin_memcpy(&u, &h, 2); return u;
}
__device__ __forceinline__ float h2f(unsigned short u){
  _Float16 h; __builtin_memcpy(&h, &u, 2); return (float)h;
}

// ---------------- dtype detection (device-side, capture-safe) ----------------
__global__ void k_detect(const unsigned short* __restrict__ xh,
                         const unsigned int* __restrict__ ew,
                         int* __restrict__ flags){
  __shared__ int s_bad, s_nz;
  int t = threadIdx.x;
  if (t == 0){ s_bad = 0; s_nz = 0; }
  __syncthreads();
  int bad = 0;
  for (int i = t; i < 512; i += 256){
    unsigned e = (xh[i] >> 7) & 0xffu;
    if (e < 96u || e > 135u) bad = 1;
  }
  if (bad) atomicOr(&s_bad, 1);
  int nz = 0;
  for (int i = t; i < 1024; i += 256)
    if ((i & 1) && ew[i] != 0u) nz = 1;
  if (nz) atomicOr(&s_nz, 1);
  __syncthreads();
  if (t == 0){
    flags[0] = s_bad ? 1 : 0;
    flags[1] = s_nz ? 0 : 1;
  }
}

__global__ void k_cvt_edges(const void* __restrict__ ei, const int* __restrict__ flags,
                            int* __restrict__ s32, int* __restrict__ d32){
  int e = blockIdx.x*256 + threadIdx.x;
  if (e >= EE) return;
  int sv, dv;
  if (flags[1]){
    const long long* p = (const long long*)ei;
    sv = (int)p[e]; dv = (int)p[EE + e];
  } else {
    const int* p = (const int*)ei;
    sv = p[e]; dv = p[EE + e];
  }
  s32[e] = ((unsigned)sv < (unsigned)NN) ? sv : 0;
  d32[e] = ((unsigned)dv < (unsigned)NN) ? dv : 0;
}

// ---------------- CSR build ----------------
__global__ void k_hist(const int* __restrict__ dst, int* __restrict__ deg){
  int e = blockIdx.x*256 + threadIdx.x;
  if (e < EE) atomicAdd(&deg[dst[e]], 1);
}

__global__ void k_blocksum(const int* __restrict__ deg, int* __restrict__ bsum){
  __shared__ int ws[4];
  int t = threadIdx.x, b = blockIdx.x;
  int s = 0;
  int i0 = b*1024 + t*4;
  #pragma unroll
  for (int j=0;j<4;j++){ int i = i0+j; if (i < NN) s += deg[i]; }
  #pragma unroll
  for (int off=32; off>=1; off>>=1) s += __shfl_xor(s, off, 64);
  if ((t&63)==0) ws[t>>6] = s;
  __syncthreads();
  if (t==0) bsum[b] = ws[0]+ws[1]+ws[2]+ws[3];
}

__global__ void k_scanb(const int* __restrict__ bsum, int* __restrict__ boff, int* __restrict__ rowptr){
  int lane = threadIdx.x;
  int v = (lane < NB) ? bsum[lane] : 0;
  int inc = v;
  #pragma unroll
  for (int off=1; off<64; off<<=1){ int u = __shfl_up(inc, off, 64); if (lane>=off) inc += u; }
  if (lane < NB) boff[lane] = inc - v;
  if (lane == 63) rowptr[NN] = inc;
}

__global__ void k_scanscatter(const int* __restrict__ deg, const int* __restrict__ boff,
                              int* __restrict__ rowptr, int* __restrict__ pos){
  __shared__ int ws[4];
  int t = threadIdx.x, b = blockIdx.x;
  int lane = t & 63, wid = t >> 6;
  int i0 = b*1024 + t*4;
  int d[4];
  #pragma unroll
  for (int j=0;j<4;j++){ int i=i0+j; d[j] = (i<NN)? deg[i] : 0; }
  int tot = d[0]+d[1]+d[2]+d[3];
  int inc = tot;
  #pragma unroll
  for (int off=1; off<64; off<<=1){ int u = __shfl_up(inc, off, 64); if (lane>=off) inc += u; }
  if (lane==63) ws[wid] = inc;
  __syncthreads();
  int woff = 0;
  for (int w=0; w<wid; w++) woff += ws[w];
  int base = boff[b] + woff + (inc - tot);
  int pre = 0;
  #pragma unroll
  for (int j=0;j<4;j++){
    int i = i0+j;
    if (i<NN){ rowptr[i] = base + pre; pos[i] = base + pre; }
    pre += d[j];
  }
}

__global__ void k_fill(const int* __restrict__ src, const int* __restrict__ dst,
                       int* __restrict__ pos, int* __restrict__ csr){
  int e = blockIdx.x*256 + threadIdx.x;
  if (e < EE){
    int d = dst[e];
    int p = atomicAdd(&pos[d], 1);
    csr[p] = src[e];
  }
}

// ---------------- weight prep: transpose + fp16 hi/lo split ------------------
__global__ void k_prep_w(const int* __restrict__ flags,
    const void* __restrict__ encW, const void* __restrict__ linW1,
    const void* __restrict__ W1, const void* __restrict__ W2,
    unsigned short* __restrict__ ph, unsigned short* __restrict__ pl)
{
  int idx = blockIdx.x*256 + threadIdx.x;   // grid covers 425984
  int fp32 = flags[0];
  const void* src; int off;
  if (idx < 16384){ int n=idx>>7, k=idx&127; src=encW; off=k*128+n; }
  else if (idx < 32768){ int o=idx-16384; int n=o>>7, k=o&127; src=linW1; off=k*128+n; }
  else if (idx < 229376){ int o=idx-32768; int l=o>>15, r=o&32767; int n=r>>7, k=r&127; src=W1; off=l*32768+k*256+n; }
  else { int o=idx-229376; int l=o>>15, r=o&32767; int n=r>>8, k=r&255; src=W2; off=l*32768+k*128+n; }
  float w = fp32 ? ((const float*)src)[off] : bf2f(((const unsigned short*)src)[off]);
  unsigned short h = f2h(w);
  ph[idx] = h;
  pl[idx] = f2h(w - h2f(h));
}

// small params -> fp32, concatenated
#define SM_ENCB 0
#define SM_LNG 128
#define SM_LNB 896
#define SM_TV 1664
#define SM_B1 1670
#define SM_MG 3206
#define SM_MB 4742
#define SM_B2 6278
#define SM_LINB1 7046
#define SM_LINW2 7174
#define SM_LINB2 7430
#define SM_TOT 7432
__global__ void k_prep_small(const int* __restrict__ flags,
    const void* s0, const void* s1, const void* s2, const void* s3,
    const void* s4, const void* s5, const void* s6, const void* s7,
    const void* s8, const void* s9, const void* s10, float* __restrict__ out)
{
  int i = blockIdx.x*256 + threadIdx.x;
  if (i >= SM_TOT) return;
  int fp32 = flags[0];
  const void* src; int off;
  if      (i < SM_LNG)  { src=s0;  off=i; }
  else if (i < SM_LNB)  { src=s1;  off=i-SM_LNG; }
  else if (i < SM_TV)   { src=s2;  off=i-SM_LNB; }
  else if (i < SM_B1)   { src=s3;  off=i-SM_TV; }
  else if (i < SM_MG)   { src=s4;  off=i-SM_B1; }
  else if (i < SM_MB)   { src=s5;  off=i-SM_MG; }
  else if (i < SM_B2)   { src=s6;  off=i-SM_MB; }
  else if (i < SM_LINB1){ src=s7;  off=i-SM_B2; }
  else if (i < SM_LINW2){ src=s8;  off=i-SM_LINB1; }
  else if (i < SM_LINB2){ src=s9;  off=i-SM_LINW2; }
  else                  { src=s10; off=i-SM_LINB2; }
  out[i] = fp32 ? ((const float*)src)[off] : bf2f(((const unsigned short*)src)[off]);
}

// msg/exp row encode: me[row][0:128] = m = relu+1e-7 (fp16); me[row][128:256] = exp(min(m*t,18)-8)
__device__ __forceinline__ void emit_me(unsigned short* me, int row, int col, float g, float tv){
  float m = g + 1e-7f;
  me[(size_t)row*256 + col] = f2h(m);
  me[(size_t)row*256 + 128 + col] = f2h(__expf(fminf(m*tv, 18.f) - 8.f));
}

// ---------------- generic f16 MFMA GEMM, K=128, tile 64x128 ------------------
template<int EPI>
__global__ __launch_bounds__(256, 4) void k_gemm(const void* __restrict__ Ap,
    const unsigned short* __restrict__ WTh, const unsigned short* __restrict__ WTl,
    const float* __restrict__ bias, float* __restrict__ C,
    int M, const int* __restrict__ flags, int aExt)
{
  __shared__ __align__(16) short lA[64*72];
  __shared__ __align__(16) short lW[128*72];

  const int tid = threadIdx.x, lane = tid & 63, wid = tid >> 6;
  const int mi = lane & 15, q = lane >> 4;
  const int rowb = blockIdx.x * 64;
  const int fp32m = flags[0];

  f32x4 acc[4][2];
  #pragma unroll
  for (int a=0;a<4;a++)
    #pragma unroll
    for (int c=0;c<2;c++){ acc[a][c][0]=0.f; acc[a][c][1]=0.f; acc[a][c][2]=0.f; acc[a][c][3]=0.f; }

  const int nW = fp32m ? 2 : 1;
  for (int pass = 0; pass < nW; ++pass){
    const unsigned short* Wp = pass ? WTl : WTh;
    for (int kc = 0; kc < 2; ++kc){
      {
        const int kv = (tid & 7) * 8, r0 = tid >> 3;
        #pragma unroll
        for (int p = 0; p < 2; ++p){
          int row = p*32 + r0, grow = rowb + row;
          uint4 d = make_uint4(0u,0u,0u,0u);
          if (grow < M){
            if (!aExt){
              d = *(const uint4*)((const unsigned short*)Ap + (size_t)grow*128 + kc*64 + kv);
            } else if (!fp32m){
              uint4 u = *(const uint4*)((const unsigned short*)Ap + (size_t)grow*128 + kc*64 + kv);
              const unsigned short* us = (const unsigned short*)&u;
              unsigned short hh[8];
              #pragma unroll
              for (int c=0;c<8;c++) hh[c] = f2h(bf2f(us[c]));
              d.x = hh[0]|((unsigned)hh[1]<<16); d.y = hh[2]|((unsigned)hh[3]<<16);
              d.z = hh[4]|((unsigned)hh[5]<<16); d.w = hh[6]|((unsigned)hh[7]<<16);
            } else {
              const float* fp = (const float*)Ap + (size_t)grow*128 + kc*64 + kv;
              float4 v0 = *(const float4*)fp, v1 = *(const float4*)(fp+4);
              unsigned short hh[8] = {f2h(v0.x),f2h(v0.y),f2h(v0.z),f2h(v0.w),
                                      f2h(v1.x),f2h(v1.y),f2h(v1.z),f2h(v1.w)};
              d.x = hh[0]|((unsigned)hh[1]<<16); d.y = hh[2]|((unsigned)hh[3]<<16);
              d.z = hh[4]|((unsigned)hh[5]<<16); d.w = hh[6]|((unsigned)hh[7]<<16);
            }
          }
          *(uint4*)&lA[row*72 + kv] = d;
        }
        #pragma unroll
        for (int p = 0; p < 4; ++p){
          int n = p*32 + r0;
          *(uint4*)&lW[n*72 + kv] = *(const uint4*)(Wp + (size_t)n*128 + kc*64 + kv);
        }
      }
      __syncthreads();
      #pragma unroll
      for (int ks = 0; ks < 2; ++ks){
        const int koff = ks*32 + q*8;
        f16x8 af[4], bw[2];
        #pragma unroll
        for (int rt=0; rt<4; rt++) af[rt] = *(const f16x8*)&lA[(rt*16+mi)*72 + koff];
        #pragma unroll
        for (int ct=0; ct<2; ct++) bw[ct] = *(const f16x8*)&lW[(wid*32 + ct*16 + mi)*72 + koff];
        #pragma unroll
        for (int rt=0; rt<4; rt++)
          #pragma unroll
          for (int ct=0; ct<2; ct++)
            acc[rt][ct] = __builtin_amdgcn_mfma_f32_16x16x32_f16(af[rt], bw[ct], acc[rt][ct], 0,0,0);
      }
      __syncthreads();
    }
  }
  #pragma unroll
  for (int ct=0; ct<2; ct++){
    const int col = wid*32 + ct*16 + mi;
    const float bf = bias[col];
    #pragma unroll
    for (int rt=0; rt<4; rt++)
      #pragma unroll
      for (int r=0; r<4; r++){
        int row = rowb + rt*16 + q*4 + r;
        if (row < M){
          float v = acc[rt][ct][r] + bf;
          if (EPI == 1) v = fmaxf(v, 0.f);
          C[(size_t)row*128 + col] = v;
        }
      }
  }
}

// ---------------- fused W1 GEMM + LN + relu: z = fp16(relu(LN(A@W1+b1))) -----
__global__ __launch_bounds__(256, 3) void k_gemm1(const unsigned short* __restrict__ Ap,
    const unsigned short* __restrict__ WTh, const unsigned short* __restrict__ WTl,
    const float* __restrict__ bias, const float* __restrict__ gam, const float* __restrict__ bet,
    unsigned short* __restrict__ z, int M, const int* __restrict__ flags)
{
  __shared__ __align__(16) short lA[64*72];
  __shared__ __align__(16) short lW[256*72];
  __shared__ float2 sred[4][64];

  const int tid = threadIdx.x, lane = tid & 63, wid = tid >> 6;
  const int mi = lane & 15, q = lane >> 4;
  const int rowb = blockIdx.x * 64;

  f32x4 acc[4][4];
  #pragma unroll
  for (int a=0;a<4;a++)
    #pragma unroll
    for (int c=0;c<4;c++){ acc[a][c][0]=0.f; acc[a][c][1]=0.f; acc[a][c][2]=0.f; acc[a][c][3]=0.f; }

  const int nW = flags[0] ? 2 : 1;
  for (int pass = 0; pass < nW; ++pass){
    const unsigned short* Wp = pass ? WTl : WTh;
    for (int kc = 0; kc < 2; ++kc){
      {
        const int kv = (tid & 7) * 8, r0 = tid >> 3;
        #pragma unroll
        for (int p = 0; p < 2; ++p){
          int row = p*32 + r0, grow = rowb + row;
          uint4 d = make_uint4(0u,0u,0u,0u);
          if (grow < M) d = *(const uint4*)(Ap + (size_t)grow*128 + kc*64 + kv);
          *(uint4*)&lA[row*72 + kv] = d;
        }
        #pragma unroll
        for (int p = 0; p < 8; ++p){
          int n = p*32 + r0;
          *(uint4*)&lW[n*72 + kv] = *(const uint4*)(Wp + (size_t)n*128 + kc*64 + kv);
        }
      }
      __syncthreads();
      #pragma unroll
      for (int ks = 0; ks < 2; ++ks){
        const int koff = ks*32 + q*8;
        f16x8 af[4], bw[4];
        #pragma unroll
        for (int rt=0; rt<4; rt++) af[rt] = *(const f16x8*)&lA[(rt*16+mi)*72 + koff];
        #pragma unroll
        for (int ct=0; ct<4; ct++) bw[ct] = *(const f16x8*)&lW[(wid*64 + ct*16 + mi)*72 + koff];
        #pragma unroll
        for (int rt=0; rt<4; rt++)
          #pragma unroll
          for (int ct=0; ct<4; ct++)
            acc[rt][ct] = __builtin_amdgcn_mfma_f32_16x16x32_f16(af[rt], bw[ct], acc[rt][ct], 0,0,0);
      }
      __syncthreads();
    }
  }
  #pragma unroll
  for (int ct=0; ct<4; ct++){
    const float bf = bias[wid*64 + ct*16 + mi];
    #pragma unroll
    for (int rt=0; rt<4; rt++)
      #pragma unroll
      for (int r=0; r<4; r++) acc[rt][ct][r] += bf;
  }
  #pragma unroll
  for (int rt=0; rt<4; rt++)
    #pragma unroll
    for (int r=0; r<4; r++){
      float s = 0.f, s2 = 0.f;
      #pragma unroll
      for (int ct=0; ct<4; ct++){ float v = acc[rt][ct][r]; s += v; s2 += v*v; }
      #pragma unroll
      for (int off=1; off<16; off<<=1){ s += __shfl_xor(s, off, 64); s2 += __shfl_xor(s2, off, 64); }
      if (mi == 0) sred[wid][rt*16 + q*4 + r] = make_float2(s, s2);
    }
  __syncthreads();
  #pragma unroll
  for (int rt=0; rt<4; rt++)
    #pragma unroll
    for (int r=0; r<4; r++){
      int rl = rt*16 + q*4 + r;
      float2 t0 = sred[0][rl], t1 = sred[1][rl], t2 = sred[2][rl], t3 = sred[3][rl];
      float s = t0.x + t1.x + t2.x + t3.x;
      float s2 = t0.y + t1.y + t2.y + t3.y;
      float m = s * (1.f/256.f);
      float var = s2 * (1.f/256.f) - m*m;
      float rs = rsqrtf(var + 1e-5f);
      int row = rowb + rl;
      if (row < M){
        #pragma unroll
        for (int ct=0; ct<4; ct++){
          int col = wid*64 + ct*16 + mi;
          float v = (acc[rt][ct][r] - m) * rs * gam[col] + bet[col];
          z[(size_t)row*256 + col] = f2h(fmaxf(v, 0.f));
        }
      }
    }
}

// ---------------- fused W2 GEMM + residual + next preLN + me -----------------
__global__ __launch_bounds__(256, 4) void k_gemm2(const unsigned short* __restrict__ Ap,
    const unsigned short* __restrict__ WTh, const unsigned short* __restrict__ WTl,
    const float* __restrict__ bias, float* __restrict__ h,
    const float* __restrict__ gam, const float* __restrict__ bet,
    const float* __restrict__ tp,
    unsigned short* __restrict__ me, unsigned short* __restrict__ hf,
    int M, const int* __restrict__ flags, int doLN)
{
  __shared__ __align__(16) short lA[64*72];
  __shared__ __align__(16) short lW[128*72];
  __shared__ float2 sred[4][64];

  const int tid = threadIdx.x, lane = tid & 63, wid = tid >> 6;
  const int mi = lane & 15, q = lane >> 4;
  const int rowb = blockIdx.x * 64;
  const float tv = tp[0];

  f32x4 acc[4][2];
  #pragma unroll
  for (int a=0;a<4;a++)
    #pragma unroll
    for (int c=0;c<2;c++){ acc[a][c][0]=0.f; acc[a][c][1]=0.f; acc[a][c][2]=0.f; acc[a][c][3]=0.f; }

  const int nW = flags[0] ? 2 : 1;
  for (int pass = 0; pass < nW; ++pass){
    const unsigned short* Wp = pass ? WTl : WTh;
    for (int kc = 0; kc < 4; ++kc){
      {
        const int kv = (tid & 7) * 8, r0 = tid >> 3;
        #pragma unroll
        for (int p = 0; p < 2; ++p){
          int row = p*32 + r0, grow = rowb + row;
          uint4 d = make_uint4(0u,0u,0u,0u);
          if (grow < M) d = *(const uint4*)(Ap + (size_t)grow*256 + kc*64 + kv);
          *(uint4*)&lA[row*72 + kv] = d;
        }
        #pragma unroll
        for (int p = 0; p < 4; ++p){
          int n = p*32 + r0;
          *(uint4*)&lW[n*72 + kv] = *(const uint4*)(Wp + (size_t)n*256 + kc*64 + kv);
        }
      }
      __syncthreads();
      #pragma unroll
      for (int ks = 0; ks < 2; ++ks){
        const int koff = ks*32 + q*8;
        f16x8 af[4], bw[2];
        #pragma unroll
        for (int rt=0; rt<4; rt++) af[rt] = *(const f16x8*)&lA[(rt*16+mi)*72 + koff];
        #pragma unroll
        for (int ct=0; ct<2; ct++) bw[ct] = *(const f16x8*)&lW[(wid*32 + ct*16 + mi)*72 + koff];
        #pragma unroll
        for (int rt=0; rt<4; rt++)
          #pragma unroll
          for (int ct=0; ct<2; ct++)
            acc[rt][ct] = __builtin_amdgcn_mfma_f32_16x16x32_f16(af[rt], bw[ct], acc[rt][ct], 0,0,0);
      }
      __syncthreads();
    }
  }
  // residual add + write h; keep hnew in acc
  #pragma unroll
  for (int ct=0; ct<2; ct++){
    const int col = wid*32 + ct*16 + mi;
    const float bf = bias[col];
    #pragma unroll
    for (int rt=0; rt<4; rt++)
      #pragma unroll
      for (int r=0; r<4; r++){
        int row = rowb + rt*16 + q*4 + r;
        if (row < M){
          float hv = acc[rt][ct][r] + bf + h[(size_t)row*128 + col];
          h[(size_t)row*128 + col] = hv;
          acc[rt][ct][r] = hv;
        }
      }
  }
  if (!doLN){
    #pragma unroll
    for (int ct=0; ct<2; ct++){
      const int col = wid*32 + ct*16 + mi;
      #pragma unroll
      for (int rt=0; rt<4; rt++)
        #pragma unroll
        for (int r=0; r<4; r++){
          int row = rowb + rt*16 + q*4 + r;
          if (row < M) hf[(size_t)row*128 + col] = f2h(acc[rt][ct][r]);
        }
    }
    return;
  }
  #pragma unroll
  for (int rt=0; rt<4; rt++)
    #pragma unroll
    for (int r=0; r<4; r++){
      float s = 0.f, s2 = 0.f;
      #pragma unroll
      for (int ct=0; ct<2; ct++){ float v = acc[rt][ct][r]; s += v; s2 += v*v; }
      #pragma unroll
      for (int off=1; off<16; off<<=1){ s += __shfl_xor(s, off, 64); s2 += __shfl_xor(s2, off, 64); }
      if (mi == 0) sred[wid][rt*16 + q*4 + r] = make_float2(s, s2);
    }
  __syncthreads();
  #pragma unroll
  for (int rt=0; rt<4; rt++)
    #pragma unroll
    for (int r=0; r<4; r++){
      int rl = rt*16 + q*4 + r;
      float2 t0 = sred[0][rl], t1 = sred[1][rl], t2 = sred[2][rl], t3 = sred[3][rl];
      float s = t0.x + t1.x + t2.x + t3.x;
      float s2 = t0.y + t1.y + t2.y + t3.y;
      float m = s * (1.f/128.f);
      float var = s2 * (1.f/128.f) - m*m;
      float rs = rsqrtf(var + 1e-5f);
      int row = rowb + rl;
      if (row < M){
        #pragma unroll
        for (int ct=0; ct<2; ct++){
          int col = wid*32 + ct*16 + mi;
          float g = fmaxf((acc[rt][ct][r] - m) * rs * gam[col] + bet[col], 0.f);
          emit_me(me, row, col, g, tv);
        }
      }
    }
}

// ---------------- layer-0 pre-LN -> me table ---------------------------------
__global__ __launch_bounds__(256,4) void k_preln0(const float* __restrict__ h,
    const float* __restrict__ gam, const float* __restrict__ bet,
    const float* __restrict__ tp, unsigned short* __restrict__ me)
{
  int wid = threadIdx.x >> 6, lane = threadIdx.x & 63;
  int row = blockIdx.x*4 + wid;
  float tv = tp[0];
  float2 v = ((const float2*)(h + (size_t)row*DD))[lane];
  float mean = wave_sum(v.x+v.y) * (1.f/128.f);
  float d0 = v.x-mean, d1 = v.y-mean;
  float var = wave_sum(d0*d0 + d1*d1) * (1.f/128.f);
  float rs = rsqrtf(var + 1e-5f);
  float o0 = fmaxf(d0*rs*gam[2*lane]   + bet[2*lane],   0.f);
  float o1 = fmaxf(d1*rs*gam[2*lane+1] + bet[2*lane+1], 0.f);
  emit_me(me, row, 2*lane,   o0, tv);
  emit_me(me, row, 2*lane+1, o1, tv);
}

// ---------------- softmax aggregation: gather precomputed (m, e') ------------
// me row layout: [m x128 | e' x128]; row NN is all-zero (invalid-lane sink).
__global__ __launch_bounds__(256,4) void k_agg(
    const unsigned short* __restrict__ me,
    const int* __restrict__ rowptr, const int* __restrict__ csr,
    unsigned short* __restrict__ obf)
{
  int wid = threadIdx.x>>6, lane = threadIdx.x&63;
  int node = blockIdx.x*4 + wid;
  int st = rowptr[node], en = rowptr[node+1];
  int quad = lane >> 4, fi = lane & 15;
  float l[8], ac[8];
  #pragma unroll
  for (int f=0; f<8; f++){ l[f]=0.f; ac[f]=0.f; }
  for (int base = st; base < en; base += 64){
    int cnt = min(64, en - base);
    int sv = (lane < cnt) ? csr[base + lane] : NN;   // NN = zero row
    for (int j = 0; j < cnt; j += 4){
      int s = __shfl(sv, j + quad, 64);
      const unsigned short* mer = me + (size_t)s*256 + fi*8;
      f16x8 mh = *(const f16x8*)(mer);
      f16x8 eh = *(const f16x8*)(mer + 128);
      #pragma unroll
      for (int f=0; f<8; f++){
        float ef = (float)eh[f];
        l[f] += ef;
        ac[f] = fmaf((float)mh[f], ef, ac[f]);
      }
    }
  }
  #pragma unroll
  for (int off=16; off<=32; off<<=1)
    #pragma unroll
    for (int f=0; f<8; f++){ l[f] += __shfl_xor(l[f], off, 64); ac[f] += __shfl_xor(ac[f], off, 64); }
  if (quad == 0){
    f16x8 mh = *(const f16x8*)(me + (size_t)node*256 + fi*8);
    bool has = en > st;
    unsigned short o[8];
    #pragma unroll
    for (int f=0; f<8; f++){
      float a = has ? (ac[f] / (l[f] + 1e-16f)) : 0.f;
      o[f] = f2h(((float)mh[f] - 1e-7f) + a);
    }
    uint4 w;
    w.x = o[0]|((unsigned)o[1]<<16); w.y = o[2]|((unsigned)o[3]<<16);
    w.z = o[4]|((unsigned)o[5]<<16); w.w = o[6]|((unsigned)o[7]<<16);
    *(uint4*)(obf + (size_t)node*DD + fi*8) = w;
  }
}

// ---------------- head ----------------
__global__ __launch_bounds__(256,4) void k_head2(const float* __restrict__ u,
    const float* __restrict__ w, const float* __restrict__ b,
    void* __restrict__ out, const int* __restrict__ flags)
{
  int wid = threadIdx.x>>6, lane = threadIdx.x&63;
  int row = blockIdx.x*4 + wid;
  const float* ur = u + (size_t)row*DD;
  float u0 = ur[lane], u1 = ur[lane+64];
  float s0 = u0*w[lane*2+0] + u1*w[(lane+64)*2+0];
  float s1 = u0*w[lane*2+1] + u1*w[(lane+64)*2+1];
  s0 = wave_sum(s0); s1 = wave_sum(s1);
  if (lane == 0){
    float o0 = s0 + b[0], o1 = s1 + b[1];
    if (flags[0]){
      ((float*)out)[row*2+0] = o0;
      ((float*)out)[row*2+1] = o1;
    } else {
      ((unsigned short*)out)[row*2+0] = f2bf(o0);
      ((unsigned short*)out)[row*2+1] = f2bf(o1);
    }
  }
}

extern "C" void kernel_launch(void* const* d_in, const int* in_sizes, int n_in,
                              void* d_out, int out_size, void* d_ws, size_t ws_size,
                              hipStream_t stream)
{
  (void)in_sizes; (void)n_in; (void)out_size; (void)ws_size;
  char* ws = (char*)d_ws;
  size_t off = 0;
  auto alloc = [&](size_t bytes) -> char* {
    char* p = ws + off;
    off = (off + bytes + 255) & ~(size_t)255;
    return p;
  };
  int* flags  = (int*)alloc(256);
  float* sm   = (float*)alloc(SM_TOT*4);
  unsigned short* planeH = (unsigned short*)alloc(425984*2);
  unsigned short* planeL = (unsigned short*)alloc(425984*2);
  int* src32  = (int*)alloc((size_t)EE*4);
  int* dst32  = (int*)alloc((size_t)EE*4);
  int* deg    = (int*)alloc((size_t)NN*4);
  int* pos    = (int*)alloc((size_t)NN*4);
  int* rowptr = (int*)alloc((size_t)(NN+1)*4);
  int* csr    = (int*)alloc((size_t)EE*4);
  int* bsum   = (int*)alloc(64*4);
  int* boff   = (int*)alloc(64*4);
  float* h    = (float*)alloc((size_t)NN*128*4);
  unsigned short* z    = (unsigned short*)alloc((size_t)NN*256*2);
  unsigned short* me   = (unsigned short*)alloc((size_t)(NN+1)*256*2);
  unsigned short* obf  = (unsigned short*)alloc((size_t)NN*128*2);
  unsigned short* hf   = (unsigned short*)alloc((size_t)NN*128*2);
  float* ob   = (float*)alloc((size_t)NN*128*4);

  k_detect<<<1,256,0,stream>>>((const unsigned short*)d_in[0], (const unsigned int*)d_in[1], flags);
  k_cvt_edges<<<(EE+255)/256,256,0,stream>>>(d_in[1], flags, src32, dst32);
  hipMemsetAsync(deg, 0, (size_t)NN*4, stream);
  hipMemsetAsync(me + (size_t)NN*256, 0, 512, stream);   // zero sink row
  k_hist<<<(EE+255)/256,256,0,stream>>>(dst32, deg);
  k_blocksum<<<NB,256,0,stream>>>(deg, bsum);
  k_scanb<<<1,64,0,stream>>>(bsum, boff, rowptr);
  k_scanscatter<<<NB,256,0,stream>>>(deg, boff, rowptr, pos);
  k_fill<<<(EE+255)/256,256,0,stream>>>(src32, dst32, pos, csr);
  k_prep_w<<<1664,256,0,stream>>>(flags, d_in[2], d_in[13], d_in[7], d_in[11], planeH, planeL);
  k_prep_small<<<30,256,0,stream>>>(flags, d_in[3], d_in[4], d_in[5], d_in[6], d_in[8],
                                    d_in[9], d_in[10], d_in[12], d_in[14], d_in[15], d_in[16], sm);

  const int GB = (NN + 63)/64;  // 782
  // encoder: h = x @ enc_W + enc_b
  k_gemm<0><<<GB,256,0,stream>>>((const void*)d_in[0], planeH + 0, planeL + 0,
                                 sm + SM_ENCB, h, NN, flags, 1);
  k_preln0<<<NN/4,256,0,stream>>>(h, sm + SM_LNG, sm + SM_LNB, sm + SM_TV, me);
  for (int i = 0; i < LL; ++i){
    k_agg<<<NN/4,256,0,stream>>>(me, rowptr, csr, obf);
    k_gemm1<<<GB,256,0,stream>>>(obf, planeH + 32768 + i*32768, planeL + 32768 + i*32768,
                                 sm + SM_B1 + i*256, sm + SM_MG + i*256, sm + SM_MB + i*256,
                                 z, NN, flags);
    int nl = (i+1 < LL) ? (i+1) : 0;
    k_gemm2<<<GB,256,0,stream>>>(z, planeH + 229376 + i*32768, planeL + 229376 + i*32768,
                                 sm + SM_B2 + i*128, h,
                                 sm + SM_LNG + nl*128, sm + SM_LNB + nl*128,
                                 sm + SM_TV + nl,
                                 me, hf, NN, flags, (i+1 < LL) ? 1 : 0);
  }
  // head: ob = relu(hf @ lin_W1 + lin_b1)
  k_gemm<1><<<GB,256,0,stream>>>((const void*)hf, planeH + 16384, planeL + 16384,
                                 sm + SM_LINB1, ob, NN, flags, 0);
  k_head2<<<NN/4,256,0,stream>>>(ob, sm + SM_LINW2, sm + SM_LINB2, d_out, flags);
}

// Round 7
// 884.149 us; speedup vs baseline: 1.0142x; 1.0142x over previous
//
#include <hip/hip_runtime.h>

#define NN 50000
#define EE 600000
#define DD 128
#define HH 256
#define LL 6
#define NB 49   // ceil(NN/1024)

typedef _Float16 f16x8 __attribute__((ext_vector_type(8)));
typedef float f32x4 __attribute__((ext_vector_type(4)));

__device__ __forceinline__ float bf2f(unsigned short u){
  unsigned int x = ((unsigned int)u) << 16; float f; __builtin_memcpy(&f, &x, 4); return f;
}
__device__ __forceinline__ unsigned short f2bf(float f){
  unsigned int x; __builtin_memcpy(&x, &f, 4);
  unsigned int lsb = (x >> 16) & 1u; x += 0x7fffu + lsb; return (unsigned short)(x >> 16);
}
__device__ __forceinline__ float wave_sum(float v){
  #pragma unroll
  for (int off = 32; off >= 1; off >>= 1) v += __shfl_xor(v, off, 64);
  return v;
}
__device__ __forceinline__ unsigned short f2h(float f){
  _Float16 h = (_Float16)f; unsigned short u; __builtin_memcpy(&u, &h, 2); return u;
}
__device__ __forceinline__ float h2f(unsigned short u){
  _Float16 h; __builtin_memcpy(&h, &u, 2); return (float)h;
}

// ---------------- dtype detection (device-side, capture-safe) ----------------
__global__ void k_detect(const unsigned short* __restrict__ xh,
                         const unsigned int* __restrict__ ew,
                         int* __restrict__ flags){
  __shared__ int s_bad, s_nz;
  int t = threadIdx.x;
  if (t == 0){ s_bad = 0; s_nz = 0; }
  __syncthreads();
  int bad = 0;
  for (int i = t; i < 512; i += 256){
    unsigned e = (xh[i] >> 7) & 0xffu;
    if (e < 96u || e > 135u) bad = 1;
  }
  if (bad) atomicOr(&s_bad, 1);
  int nz = 0;
  for (int i = t; i < 1024; i += 256)
    if ((i & 1) && ew[i] != 0u) nz = 1;
  if (nz) atomicOr(&s_nz, 1);
  __syncthreads();
  if (t == 0){
    flags[0] = s_bad ? 1 : 0;
    flags[1] = s_nz ? 0 : 1;
  }
}

__global__ void k_cvt_edges(const void* __restrict__ ei, const int* __restrict__ flags,
                            int* __restrict__ s32, int* __restrict__ d32){
  int e = blockIdx.x*256 + threadIdx.x;
  if (e >= EE) return;
  int sv, dv;
  if (flags[1]){
    const long long* p = (const long long*)ei;
    sv = (int)p[e]; dv = (int)p[EE + e];
  } else {
    const int* p = (const int*)ei;
    sv = p[e]; dv = p[EE + e];
  }
  s32[e] = ((unsigned)sv < (unsigned)NN) ? sv : 0;
  d32[e] = ((unsigned)dv < (unsigned)NN) ? dv : 0;
}

// ---------------- CSR build ----------------
__global__ void k_hist(const int* __restrict__ dst, int* __restrict__ deg){
  int e = blockIdx.x*256 + threadIdx.x;
  if (e < EE) atomicAdd(&deg[dst[e]], 1);
}

__global__ void k_blocksum(const int* __restrict__ deg, int* __restrict__ bsum){
  __shared__ int ws[4];
  int t = threadIdx.x, b = blockIdx.x;
  int s = 0;
  int i0 = b*1024 + t*4;
  #pragma unroll
  for (int j=0;j<4;j++){ int i = i0+j; if (i < NN) s += deg[i]; }
  #pragma unroll
  for (int off=32; off>=1; off>>=1) s += __shfl_xor(s, off, 64);
  if ((t&63)==0) ws[t>>6] = s;
  __syncthreads();
  if (t==0) bsum[b] = ws[0]+ws[1]+ws[2]+ws[3];
}

__global__ void k_scanb(const int* __restrict__ bsum, int* __restrict__ boff, int* __restrict__ rowptr){
  int lane = threadIdx.x;
  int v = (lane < NB) ? bsum[lane] : 0;
  int inc = v;
  #pragma unroll
  for (int off=1; off<64; off<<=1){ int u = __shfl_up(inc, off, 64); if (lane>=off) inc += u; }
  if (lane < NB) boff[lane] = inc - v;
  if (lane == 63) rowptr[NN] = inc;
}

__global__ void k_scanscatter(const int* __restrict__ deg, const int* __restrict__ boff,
                              int* __restrict__ rowptr, int* __restrict__ pos){
  __shared__ int ws[4];
  int t = threadIdx.x, b = blockIdx.x;
  int lane = t & 63, wid = t >> 6;
  int i0 = b*1024 + t*4;
  int d[4];
  #pragma unroll
  for (int j=0;j<4;j++){ int i=i0+j; d[j] = (i<NN)? deg[i] : 0; }
  int tot = d[0]+d[1]+d[2]+d[3];
  int inc = tot;
  #pragma unroll
  for (int off=1; off<64; off<<=1){ int u = __shfl_up(inc, off, 64); if (lane>=off) inc += u; }
  if (lane==63) ws[wid] = inc;
  __syncthreads();
  int woff = 0;
  for (int w=0; w<wid; w++) woff += ws[w];
  int base = boff[b] + woff + (inc - tot);
  int pre = 0;
  #pragma unroll
  for (int j=0;j<4;j++){
    int i = i0+j;
    if (i<NN){ rowptr[i] = base + pre; pos[i] = base + pre; }
    pre += d[j];
  }
}

__global__ void k_fill(const int* __restrict__ src, const int* __restrict__ dst,
                       int* __restrict__ pos, int* __restrict__ csr){
  int e = blockIdx.x*256 + threadIdx.x;
  if (e < EE){
    int d = dst[e];
    int p = atomicAdd(&pos[d], 1);
    csr[p] = src[e];
  }
}

// ---------------- weight prep: transpose + fp16 hi/lo split ------------------
__global__ void k_prep_w(const int* __restrict__ flags,
    const void* __restrict__ encW, const void* __restrict__ linW1,
    const void* __restrict__ W1, const void* __restrict__ W2,
    unsigned short* __restrict__ ph, unsigned short* __restrict__ pl)
{
  int idx = blockIdx.x*256 + threadIdx.x;   // grid covers 425984
  int fp32 = flags[0];
  const void* src; int off;
  if (idx < 16384){ int n=idx>>7, k=idx&127; src=encW; off=k*128+n; }
  else if (idx < 32768){ int o=idx-16384; int n=o>>7, k=o&127; src=linW1; off=k*128+n; }
  else if (idx < 229376){ int o=idx-32768; int l=o>>15, r=o&32767; int n=r>>7, k=r&127; src=W1; off=l*32768+k*256+n; }
  else { int o=idx-229376; int l=o>>15, r=o&32767; int n=r>>8, k=r&255; src=W2; off=l*32768+k*128+n; }
  float w = fp32 ? ((const float*)src)[off] : bf2f(((const unsigned short*)src)[off]);
  unsigned short h = f2h(w);
  ph[idx] = h;
  pl[idx] = f2h(w - h2f(h));
}

// small params -> fp32, concatenated
#define SM_ENCB 0
#define SM_LNG 128
#define SM_LNB 896
#define SM_TV 1664
#define SM_B1 1670
#define SM_MG 3206
#define SM_MB 4742
#define SM_B2 6278
#define SM_LINB1 7046
#define SM_LINW2 7174
#define SM_LINB2 7430
#define SM_TOT 7432
__global__ void k_prep_small(const int* __restrict__ flags,
    const void* s0, const void* s1, const void* s2, const void* s3,
    const void* s4, const void* s5, const void* s6, const void* s7,
    const void* s8, const void* s9, const void* s10, float* __restrict__ out)
{
  int i = blockIdx.x*256 + threadIdx.x;
  if (i >= SM_TOT) return;
  int fp32 = flags[0];
  const void* src; int off;
  if      (i < SM_LNG)  { src=s0;  off=i; }
  else if (i < SM_LNB)  { src=s1;  off=i-SM_LNG; }
  else if (i < SM_TV)   { src=s2;  off=i-SM_LNB; }
  else if (i < SM_B1)   { src=s3;  off=i-SM_TV; }
  else if (i < SM_MG)   { src=s4;  off=i-SM_B1; }
  else if (i < SM_MB)   { src=s5;  off=i-SM_MG; }
  else if (i < SM_B2)   { src=s6;  off=i-SM_MB; }
  else if (i < SM_LINB1){ src=s7;  off=i-SM_B2; }
  else if (i < SM_LINW2){ src=s8;  off=i-SM_LINB1; }
  else if (i < SM_LINB2){ src=s9;  off=i-SM_LINW2; }
  else                  { src=s10; off=i-SM_LINB2; }
  out[i] = fp32 ? ((const float*)src)[off] : bf2f(((const unsigned short*)src)[off]);
}

// me row: [m x128 | e' x128], e' = exp(min(m*t,18)-8); row NN = zeros (sink)
__device__ __forceinline__ void emit_me(unsigned short* me, int row, int col, float g, float tv){
  float m = g + 1e-7f;
  me[(size_t)row*256 + col] = f2h(m);
  me[(size_t)row*256 + 128 + col] = f2h(__expf(fminf(m*tv, 18.f) - 8.f));
}

// ---------------- generic f16 MFMA GEMM, K=128, tile 64x128 ------------------
// EPI: 0 = store fp32, 1 = relu+store fp32, 3 = store fp16.
template<int EPI>
__global__ __launch_bounds__(256, 4) void k_gemm(const void* __restrict__ Ap,
    const unsigned short* __restrict__ WTh, const unsigned short* __restrict__ WTl,
    const float* __restrict__ bias, void* __restrict__ Cv,
    int M, const int* __restrict__ flags, int aExt)
{
  __shared__ __align__(16) short lA[64*72];
  __shared__ __align__(16) short lW[128*72];

  const int tid = threadIdx.x, lane = tid & 63, wid = tid >> 6;
  const int mi = lane & 15, q = lane >> 4;
  const int rowb = blockIdx.x * 64;
  const int fp32m = flags[0];

  f32x4 acc[4][2];
  #pragma unroll
  for (int a=0;a<4;a++)
    #pragma unroll
    for (int c=0;c<2;c++){ acc[a][c][0]=0.f; acc[a][c][1]=0.f; acc[a][c][2]=0.f; acc[a][c][3]=0.f; }

  const int nW = fp32m ? 2 : 1;
  for (int pass = 0; pass < nW; ++pass){
    const unsigned short* Wp = pass ? WTl : WTh;
    for (int kc = 0; kc < 2; ++kc){
      {
        const int kv = (tid & 7) * 8, r0 = tid >> 3;
        #pragma unroll
        for (int p = 0; p < 2; ++p){
          int row = p*32 + r0, grow = rowb + row;
          uint4 d = make_uint4(0u,0u,0u,0u);
          if (grow < M){
            if (!aExt){
              d = *(const uint4*)((const unsigned short*)Ap + (size_t)grow*128 + kc*64 + kv);
            } else if (!fp32m){
              uint4 u = *(const uint4*)((const unsigned short*)Ap + (size_t)grow*128 + kc*64 + kv);
              const unsigned short* us = (const unsigned short*)&u;
              unsigned short hh[8];
              #pragma unroll
              for (int c=0;c<8;c++) hh[c] = f2h(bf2f(us[c]));
              d.x = hh[0]|((unsigned)hh[1]<<16); d.y = hh[2]|((unsigned)hh[3]<<16);
              d.z = hh[4]|((unsigned)hh[5]<<16); d.w = hh[6]|((unsigned)hh[7]<<16);
            } else {
              const float* fp = (const float*)Ap + (size_t)grow*128 + kc*64 + kv;
              float4 v0 = *(const float4*)fp, v1 = *(const float4*)(fp+4);
              unsigned short hh[8] = {f2h(v0.x),f2h(v0.y),f2h(v0.z),f2h(v0.w),
                                      f2h(v1.x),f2h(v1.y),f2h(v1.z),f2h(v1.w)};
              d.x = hh[0]|((unsigned)hh[1]<<16); d.y = hh[2]|((unsigned)hh[3]<<16);
              d.z = hh[4]|((unsigned)hh[5]<<16); d.w = hh[6]|((unsigned)hh[7]<<16);
            }
          }
          *(uint4*)&lA[row*72 + kv] = d;
        }
        #pragma unroll
        for (int p = 0; p < 4; ++p){
          int n = p*32 + r0;
          *(uint4*)&lW[n*72 + kv] = *(const uint4*)(Wp + (size_t)n*128 + kc*64 + kv);
        }
      }
      __syncthreads();
      #pragma unroll
      for (int ks = 0; ks < 2; ++ks){
        const int koff = ks*32 + q*8;
        f16x8 af[4], bw[2];
        #pragma unroll
        for (int rt=0; rt<4; rt++) af[rt] = *(const f16x8*)&lA[(rt*16+mi)*72 + koff];
        #pragma unroll
        for (int ct=0; ct<2; ct++) bw[ct] = *(const f16x8*)&lW[(wid*32 + ct*16 + mi)*72 + koff];
        #pragma unroll
        for (int rt=0; rt<4; rt++)
          #pragma unroll
          for (int ct=0; ct<2; ct++)
            acc[rt][ct] = __builtin_amdgcn_mfma_f32_16x16x32_f16(af[rt], bw[ct], acc[rt][ct], 0,0,0);
      }
      __syncthreads();
    }
  }
  #pragma unroll
  for (int ct=0; ct<2; ct++){
    const int col = wid*32 + ct*16 + mi;
    const float bf = bias[col];
    #pragma unroll
    for (int rt=0; rt<4; rt++)
      #pragma unroll
      for (int r=0; r<4; r++){
        int row = rowb + rt*16 + q*4 + r;
        if (row < M){
          float v = acc[rt][ct][r] + bf;
          if (EPI == 1) v = fmaxf(v, 0.f);
          if (EPI == 3) ((unsigned short*)Cv)[(size_t)row*128 + col] = f2h(v);
          else          ((float*)Cv)[(size_t)row*128 + col] = v;
        }
      }
  }
}

// ---------------- fused W1 GEMM + LN + relu: z = fp16(relu(LN(A@W1+b1))) -----
__global__ __launch_bounds__(256, 3) void k_gemm1(const unsigned short* __restrict__ Ap,
    const unsigned short* __restrict__ WTh, const unsigned short* __restrict__ WTl,
    const float* __restrict__ bias, const float* __restrict__ gam, const float* __restrict__ bet,
    unsigned short* __restrict__ z, int M, const int* __restrict__ flags)
{
  __shared__ __align__(16) short lA[64*72];
  __shared__ __align__(16) short lW[256*72];
  __shared__ float2 sred[4][64];

  const int tid = threadIdx.x, lane = tid & 63, wid = tid >> 6;
  const int mi = lane & 15, q = lane >> 4;
  const int rowb = blockIdx.x * 64;

  f32x4 acc[4][4];
  #pragma unroll
  for (int a=0;a<4;a++)
    #pragma unroll
    for (int c=0;c<4;c++){ acc[a][c][0]=0.f; acc[a][c][1]=0.f; acc[a][c][2]=0.f; acc[a][c][3]=0.f; }

  const int nW = flags[0] ? 2 : 1;
  for (int pass = 0; pass < nW; ++pass){
    const unsigned short* Wp = pass ? WTl : WTh;
    for (int kc = 0; kc < 2; ++kc){
      {
        const int kv = (tid & 7) * 8, r0 = tid >> 3;
        #pragma unroll
        for (int p = 0; p < 2; ++p){
          int row = p*32 + r0, grow = rowb + row;
          uint4 d = make_uint4(0u,0u,0u,0u);
          if (grow < M) d = *(const uint4*)(Ap + (size_t)grow*128 + kc*64 + kv);
          *(uint4*)&lA[row*72 + kv] = d;
        }
        #pragma unroll
        for (int p = 0; p < 8; ++p){
          int n = p*32 + r0;
          *(uint4*)&lW[n*72 + kv] = *(const uint4*)(Wp + (size_t)n*128 + kc*64 + kv);
        }
      }
      __syncthreads();
      #pragma unroll
      for (int ks = 0; ks < 2; ++ks){
        const int koff = ks*32 + q*8;
        f16x8 af[4], bw[4];
        #pragma unroll
        for (int rt=0; rt<4; rt++) af[rt] = *(const f16x8*)&lA[(rt*16+mi)*72 + koff];
        #pragma unroll
        for (int ct=0; ct<4; ct++) bw[ct] = *(const f16x8*)&lW[(wid*64 + ct*16 + mi)*72 + koff];
        #pragma unroll
        for (int rt=0; rt<4; rt++)
          #pragma unroll
          for (int ct=0; ct<4; ct++)
            acc[rt][ct] = __builtin_amdgcn_mfma_f32_16x16x32_f16(af[rt], bw[ct], acc[rt][ct], 0,0,0);
      }
      __syncthreads();
    }
  }
  #pragma unroll
  for (int ct=0; ct<4; ct++){
    const float bf = bias[wid*64 + ct*16 + mi];
    #pragma unroll
    for (int rt=0; rt<4; rt++)
      #pragma unroll
      for (int r=0; r<4; r++) acc[rt][ct][r] += bf;
  }
  #pragma unroll
  for (int rt=0; rt<4; rt++)
    #pragma unroll
    for (int r=0; r<4; r++){
      float s = 0.f, s2 = 0.f;
      #pragma unroll
      for (int ct=0; ct<4; ct++){ float v = acc[rt][ct][r]; s += v; s2 += v*v; }
      #pragma unroll
      for (int off=1; off<16; off<<=1){ s += __shfl_xor(s, off, 64); s2 += __shfl_xor(s2, off, 64); }
      if (mi == 0) sred[wid][rt*16 + q*4 + r] = make_float2(s, s2);
    }
  __syncthreads();
  #pragma unroll
  for (int rt=0; rt<4; rt++)
    #pragma unroll
    for (int r=0; r<4; r++){
      int rl = rt*16 + q*4 + r;
      float2 t0 = sred[0][rl], t1 = sred[1][rl], t2 = sred[2][rl], t3 = sred[3][rl];
      float s = t0.x + t1.x + t2.x + t3.x;
      float s2 = t0.y + t1.y + t2.y + t3.y;
      float m = s * (1.f/256.f);
      float var = s2 * (1.f/256.f) - m*m;
      float rs = rsqrtf(var + 1e-5f);
      int row = rowb + rl;
      if (row < M){
        #pragma unroll
        for (int ct=0; ct<4; ct++){
          int col = wid*64 + ct*16 + mi;
          float v = (acc[rt][ct][r] - m) * rs * gam[col] + bet[col];
          z[(size_t)row*256 + col] = f2h(fmaxf(v, 0.f));
        }
      }
    }
}

// ---------------- fused W2 GEMM + residual(fp16 h) + next preLN + me ---------
__global__ __launch_bounds__(256, 4) void k_gemm2(const unsigned short* __restrict__ Ap,
    const unsigned short* __restrict__ WTh, const unsigned short* __restrict__ WTl,
    const float* __restrict__ bias, unsigned short* __restrict__ h16,
    const float* __restrict__ gam, const float* __restrict__ bet,
    const float* __restrict__ tp,
    unsigned short* __restrict__ me,
    int M, const int* __restrict__ flags, int doLN)
{
  __shared__ __align__(16) short lA[64*72];
  __shared__ __align__(16) short lW[128*72];
  __shared__ float2 sred[4][64];

  const int tid = threadIdx.x, lane = tid & 63, wid = tid >> 6;
  const int mi = lane & 15, q = lane >> 4;
  const int rowb = blockIdx.x * 64;
  const float tv = tp[0];

  f32x4 acc[4][2];
  #pragma unroll
  for (int a=0;a<4;a++)
    #pragma unroll
    for (int c=0;c<2;c++){ acc[a][c][0]=0.f; acc[a][c][1]=0.f; acc[a][c][2]=0.f; acc[a][c][3]=0.f; }

  const int nW = flags[0] ? 2 : 1;
  for (int pass = 0; pass < nW; ++pass){
    const unsigned short* Wp = pass ? WTl : WTh;
    for (int kc = 0; kc < 4; ++kc){
      {
        const int kv = (tid & 7) * 8, r0 = tid >> 3;
        #pragma unroll
        for (int p = 0; p < 2; ++p){
          int row = p*32 + r0, grow = rowb + row;
          uint4 d = make_uint4(0u,0u,0u,0u);
          if (grow < M) d = *(const uint4*)(Ap + (size_t)grow*256 + kc*64 + kv);
          *(uint4*)&lA[row*72 + kv] = d;
        }
        #pragma unroll
        for (int p = 0; p < 4; ++p){
          int n = p*32 + r0;
          *(uint4*)&lW[n*72 + kv] = *(const uint4*)(Wp + (size_t)n*256 + kc*64 + kv);
        }
      }
      __syncthreads();
      #pragma unroll
      for (int ks = 0; ks < 2; ++ks){
        const int koff = ks*32 + q*8;
        f16x8 af[4], bw[2];
        #pragma unroll
        for (int rt=0; rt<4; rt++) af[rt] = *(const f16x8*)&lA[(rt*16+mi)*72 + koff];
        #pragma unroll
        for (int ct=0; ct<2; ct++) bw[ct] = *(const f16x8*)&lW[(wid*32 + ct*16 + mi)*72 + koff];
        #pragma unroll
        for (int rt=0; rt<4; rt++)
          #pragma unroll
          for (int ct=0; ct<2; ct++)
            acc[rt][ct] = __builtin_amdgcn_mfma_f32_16x16x32_f16(af[rt], bw[ct], acc[rt][ct], 0,0,0);
      }
      __syncthreads();
    }
  }
  // residual add (fp16 h) + write back; keep hnew in acc
  #pragma unroll
  for (int ct=0; ct<2; ct++){
    const int col = wid*32 + ct*16 + mi;
    const float bf = bias[col];
    #pragma unroll
    for (int rt=0; rt<4; rt++)
      #pragma unroll
      for (int r=0; r<4; r++){
        int row = rowb + rt*16 + q*4 + r;
        if (row < M){
          float hv = acc[rt][ct][r] + bf + h2f(h16[(size_t)row*128 + col]);
          h16[(size_t)row*128 + col] = f2h(hv);
          acc[rt][ct][r] = hv;
        }
      }
  }
  if (!doLN) return;
  #pragma unroll
  for (int rt=0; rt<4; rt++)
    #pragma unroll
    for (int r=0; r<4; r++){
      float s = 0.f, s2 = 0.f;
      #pragma unroll
      for (int ct=0; ct<2; ct++){ float v = acc[rt][ct][r]; s += v; s2 += v*v; }
      #pragma unroll
      for (int off=1; off<16; off<<=1){ s += __shfl_xor(s, off, 64); s2 += __shfl_xor(s2, off, 64); }
      if (mi == 0) sred[wid][rt*16 + q*4 + r] = make_float2(s, s2);
    }
  __syncthreads();
  #pragma unroll
  for (int rt=0; rt<4; rt++)
    #pragma unroll
    for (int r=0; r<4; r++){
      int rl = rt*16 + q*4 + r;
      float2 t0 = sred[0][rl], t1 = sred[1][rl], t2 = sred[2][rl], t3 = sred[3][rl];
      float s = t0.x + t1.x + t2.x + t3.x;
      float s2 = t0.y + t1.y + t2.y + t3.y;
      float m = s * (1.f/128.f);
      float var = s2 * (1.f/128.f) - m*m;
      float rs = rsqrtf(var + 1e-5f);
      int row = rowb + rl;
      if (row < M){
        #pragma unroll
        for (int ct=0; ct<2; ct++){
          int col = wid*32 + ct*16 + mi;
          float g = fmaxf((acc[rt][ct][r] - m) * rs * gam[col] + bet[col], 0.f);
          emit_me(me, row, col, g, tv);
        }
      }
    }
}

// ---------------- layer-0 pre-LN (fp16 h) -> me table ------------------------
__global__ __launch_bounds__(256,4) void k_preln0(const unsigned short* __restrict__ h16,
    const float* __restrict__ gam, const float* __restrict__ bet,
    const float* __restrict__ tp, unsigned short* __restrict__ me)
{
  int wid = threadIdx.x >> 6, lane = threadIdx.x & 63;
  int row = blockIdx.x*4 + wid;
  float tv = tp[0];
  unsigned u = ((const unsigned*)(h16 + (size_t)row*DD))[lane];
  float v0 = h2f((unsigned short)(u & 0xffffu));
  float v1 = h2f((unsigned short)(u >> 16));
  float mean = wave_sum(v0+v1) * (1.f/128.f);
  float d0 = v0-mean, d1 = v1-mean;
  float var = wave_sum(d0*d0 + d1*d1) * (1.f/128.f);
  float rs = rsqrtf(var + 1e-5f);
  float o0 = fmaxf(d0*rs*gam[2*lane]   + bet[2*lane],   0.f);
  float o1 = fmaxf(d1*rs*gam[2*lane+1] + bet[2*lane+1], 0.f);
  emit_me(me, row, 2*lane,   o0, tv);
  emit_me(me, row, 2*lane+1, o1, tv);
}

// ---------------- softmax aggregation: 8 edges/iter, gather (m, e') ----------
__global__ __launch_bounds__(256,4) void k_agg(
    const unsigned short* __restrict__ me,
    const int* __restrict__ rowptr, const int* __restrict__ csr,
    unsigned short* __restrict__ obf)
{
  int wid = threadIdx.x>>6, lane = threadIdx.x&63;
  int node = blockIdx.x*4 + wid;
  int st = rowptr[node], en = rowptr[node+1];
  int quad = lane >> 4, fi = lane & 15;
  float l[8], ac[8];
  #pragma unroll
  for (int f=0; f<8; f++){ l[f]=0.f; ac[f]=0.f; }
  for (int base = st; base < en; base += 64){
    int cnt = min(64, en - base);
    int sv = (lane < cnt) ? csr[base + lane] : NN;   // NN = zero sink row
    for (int j = 0; j < cnt; j += 8){
      int s0i = __shfl(sv, j + quad, 64);
      int s1i = __shfl(sv, j + 4 + quad, 64);
      bool two = (j + 4) < cnt;
      const unsigned short* mer0 = me + (size_t)s0i*256 + fi*8;
      f16x8 mh0 = *(const f16x8*)(mer0);
      f16x8 eh0 = *(const f16x8*)(mer0 + 128);
      if (two){
        const unsigned short* mer1 = me + (size_t)s1i*256 + fi*8;
        f16x8 mh1 = *(const f16x8*)(mer1);
        f16x8 eh1 = *(const f16x8*)(mer1 + 128);
        #pragma unroll
        for (int f=0; f<8; f++){
          l[f]  = fmaf((float)eh0[f], 1.f, l[f]);
          ac[f] = fmaf((float)mh0[f], (float)eh0[f], ac[f]);
          l[f]  = fmaf((float)eh1[f], 1.f, l[f]);
          ac[f] = fmaf((float)mh1[f], (float)eh1[f], ac[f]);
        }
      } else {
        #pragma unroll
        for (int f=0; f<8; f++){
          l[f]  = fmaf((float)eh0[f], 1.f, l[f]);
          ac[f] = fmaf((float)mh0[f], (float)eh0[f], ac[f]);
        }
      }
    }
  }
  #pragma unroll
  for (int off=16; off<=32; off<<=1)
    #pragma unroll
    for (int f=0; f<8; f++){ l[f] += __shfl_xor(l[f], off, 64); ac[f] += __shfl_xor(ac[f], off, 64); }
  if (quad == 0){
    f16x8 mh = *(const f16x8*)(me + (size_t)node*256 + fi*8);
    unsigned short o[8];
    #pragma unroll
    for (int f=0; f<8; f++){
      float a = ac[f] / (l[f] + 1e-16f);
      o[f] = f2h(((float)mh[f] - 1e-7f) + a);
    }
    uint4 w;
    w.x = o[0]|((unsigned)o[1]<<16); w.y = o[2]|((unsigned)o[3]<<16);
    w.z = o[4]|((unsigned)o[5]<<16); w.w = o[6]|((unsigned)o[7]<<16);
    *(uint4*)(obf + (size_t)node*DD + fi*8) = w;
  }
}

// ---------------- head ----------------
__global__ __launch_bounds__(256,4) void k_head2(const float* __restrict__ u,
    const float* __restrict__ w, const float* __restrict__ b,
    void* __restrict__ out, const int* __restrict__ flags)
{
  int wid = threadIdx.x>>6, lane = threadIdx.x&63;
  int row = blockIdx.x*4 + wid;
  const float* ur = u + (size_t)row*DD;
  float u0 = ur[lane], u1 = ur[lane+64];
  float s0 = u0*w[lane*2+0] + u1*w[(lane+64)*2+0];
  float s1 = u0*w[lane*2+1] + u1*w[(lane+64)*2+1];
  s0 = wave_sum(s0); s1 = wave_sum(s1);
  if (lane == 0){
    float o0 = s0 + b[0], o1 = s1 + b[1];
    if (flags[0]){
      ((float*)out)[row*2+0] = o0;
      ((float*)out)[row*2+1] = o1;
    } else {
      ((unsigned short*)out)[row*2+0] = f2bf(o0);
      ((unsigned short*)out)[row*2+1] = f2bf(o1);
    }
  }
}

extern "C" void kernel_launch(void* const* d_in, const int* in_sizes, int n_in,
                              void* d_out, int out_size, void* d_ws, size_t ws_size,
                              hipStream_t stream)
{
  (void)in_sizes; (void)n_in; (void)out_size; (void)ws_size;
  char* ws = (char*)d_ws;
  size_t off = 0;
  auto alloc = [&](size_t bytes) -> char* {
    char* p = ws + off;
    off = (off + bytes + 255) & ~(size_t)255;
    return p;
  };
  int* flags  = (int*)alloc(256);
  float* sm   = (float*)alloc(SM_TOT*4);
  unsigned short* planeH = (unsigned short*)alloc(425984*2);
  unsigned short* planeL = (unsigned short*)alloc(425984*2);
  int* src32  = (int*)alloc((size_t)EE*4);
  int* dst32  = (int*)alloc((size_t)EE*4);
  int* deg    = (int*)alloc((size_t)NN*4);
  int* pos    = (int*)alloc((size_t)NN*4);
  int* rowptr = (int*)alloc((size_t)(NN+1)*4);
  int* csr    = (int*)alloc((size_t)EE*4);
  int* bsum   = (int*)alloc(64*4);
  int* boff   = (int*)alloc(64*4);
  unsigned short* h16 = (unsigned short*)alloc((size_t)NN*128*2);
  unsigned short* z    = (unsigned short*)alloc((size_t)NN*256*2);
  unsigned short* me   = (unsigned short*)alloc((size_t)(NN+1)*256*2);
  unsigned short* obf  = (unsigned short*)alloc((size_t)NN*128*2);
  float* ob   = (float*)alloc((size_t)NN*128*4);

  k_detect<<<1,256,0,stream>>>((const unsigned short*)d_in[0], (const unsigned int*)d_in[1], flags);
  k_cvt_edges<<<(EE+255)/256,256,0,stream>>>(d_in[1], flags, src32, dst32);
  hipMemsetAsync(deg, 0, (size_t)NN*4, stream);
  hipMemsetAsync(me + (size_t)NN*256, 0, 512, stream);   // zero sink row
  k_hist<<<(EE+255)/256,256,0,stream>>>(dst32, deg);
  k_blocksum<<<NB,256,0,stream>>>(deg, bsum);
  k_scanb<<<1,64,0,stream>>>(bsum, boff, rowptr);
  k_scanscatter<<<NB,256,0,stream>>>(deg, boff, rowptr, pos);
  k_fill<<<(EE+255)/256,256,0,stream>>>(src32, dst32, pos, csr);
  k_prep_w<<<1664,256,0,stream>>>(flags, d_in[2], d_in[13], d_in[7], d_in[11], planeH, planeL);
  k_prep_small<<<30,256,0,stream>>>(flags, d_in[3], d_in[4], d_in[5], d_in[6], d_in[8],
                                    d_in[9], d_in[10], d_in[12], d_in[14], d_in[15], d_in[16], sm);

  const int GB = (NN + 63)/64;  // 782
  // encoder: h16 = fp16(x @ enc_W + enc_b)
  k_gemm<3><<<GB,256,0,stream>>>((const void*)d_in[0], planeH + 0, planeL + 0,
                                 sm + SM_ENCB, (void*)h16, NN, flags, 1);
  k_preln0<<<NN/4,256,0,stream>>>(h16, sm + SM_LNG, sm + SM_LNB, sm + SM_TV, me);
  for (int i = 0; i < LL; ++i){
    k_agg<<<NN/4,256,0,stream>>>(me, rowptr, csr, obf);
    k_gemm1<<<GB,256,0,stream>>>(obf, planeH + 32768 + i*32768, planeL + 32768 + i*32768,
                                 sm + SM_B1 + i*256, sm + SM_MG + i*256, sm + SM_MB + i*256,
                                 z, NN, flags);
    int nl = (i+1 < LL) ? (i+1) : 0;
    k_gemm2<<<GB,256,0,stream>>>(z, planeH + 229376 + i*32768, planeL + 229376 + i*32768,
                                 sm + SM_B2 + i*128, h16,
                                 sm + SM_LNG + nl*128, sm + SM_LNB + nl*128,
                                 sm + SM_TV + nl,
                                 me, NN, flags, (i+1 < LL) ? 1 : 0);
  }
  // head: ob = relu(h16 @ lin_W1 + lin_b1)
  k_gemm<1><<<GB,256,0,stream>>>((const void*)h16, planeH + 16384, planeL + 16384,
                                 sm + SM_LINB1, (void*)ob, NN, flags, 0);
  k_head2<<<NN/4,256,0,stream>>>(ob, sm + SM_LINW2, sm + SM_LINB2, d_out, flags);
}

// Round 8
// 883.843 us; speedup vs baseline: 1.0146x; 1.0003x over previous
//
#include <hip/hip_runtime.h>

#define NN 50000
#define EE 600000
#define DD 128
#define HH 256
#define LL 6
#define NB 49   // ceil(NN/1024)

typedef _Float16 f16x8 __attribute__((ext_vector_type(8)));
typedef float f32x4 __attribute__((ext_vector_type(4)));

__device__ __forceinline__ float bf2f(unsigned short u){
  unsigned int x = ((unsigned int)u) << 16; float f; __builtin_memcpy(&f, &x, 4); return f;
}
__device__ __forceinline__ unsigned short f2bf(float f){
  unsigned int x; __builtin_memcpy(&x, &f, 4);
  unsigned int lsb = (x >> 16) & 1u; x += 0x7fffu + lsb; return (unsigned short)(x >> 16);
}
__device__ __forceinline__ float wave_sum(float v){
  #pragma unroll
  for (int off = 32; off >= 1; off >>= 1) v += __shfl_xor(v, off, 64);
  return v;
}
__device__ __forceinline__ unsigned short f2h(float f){
  _Float16 h = (_Float16)f; unsigned short u; __builtin_memcpy(&u, &h, 2); return u;
}
__device__ __forceinline__ float h2f(unsigned short u){
  _Float16 h; __builtin_memcpy(&h, &u, 2); return (float)h;
}

// ---------------- dtype detection (device-side, capture-safe) ----------------
__global__ void k_detect(const unsigned short* __restrict__ xh,
                         const unsigned int* __restrict__ ew,
                         int* __restrict__ flags){
  __shared__ int s_bad, s_nz;
  int t = threadIdx.x;
  if (t == 0){ s_bad = 0; s_nz = 0; }
  __syncthreads();
  int bad = 0;
  for (int i = t; i < 512; i += 256){
    unsigned e = (xh[i] >> 7) & 0xffu;
    if (e < 96u || e > 135u) bad = 1;
  }
  if (bad) atomicOr(&s_bad, 1);
  int nz = 0;
  for (int i = t; i < 1024; i += 256)
    if ((i & 1) && ew[i] != 0u) nz = 1;
  if (nz) atomicOr(&s_nz, 1);
  __syncthreads();
  if (t == 0){
    flags[0] = s_bad ? 1 : 0;
    flags[1] = s_nz ? 0 : 1;
  }
}

__global__ void k_cvt_edges(const void* __restrict__ ei, const int* __restrict__ flags,
                            int* __restrict__ s32, int* __restrict__ d32){
  int e = blockIdx.x*256 + threadIdx.x;
  if (e >= EE) return;
  int sv, dv;
  if (flags[1]){
    const long long* p = (const long long*)ei;
    sv = (int)p[e]; dv = (int)p[EE + e];
  } else {
    const int* p = (const int*)ei;
    sv = p[e]; dv = p[EE + e];
  }
  s32[e] = ((unsigned)sv < (unsigned)NN) ? sv : 0;
  d32[e] = ((unsigned)dv < (unsigned)NN) ? dv : 0;
}

// ---------------- CSR build ----------------
__global__ void k_hist(const int* __restrict__ dst, int* __restrict__ deg){
  int e = blockIdx.x*256 + threadIdx.x;
  if (e < EE) atomicAdd(&deg[dst[e]], 1);
}

__global__ void k_blocksum(const int* __restrict__ deg, int* __restrict__ bsum){
  __shared__ int ws[4];
  int t = threadIdx.x, b = blockIdx.x;
  int s = 0;
  int i0 = b*1024 + t*4;
  #pragma unroll
  for (int j=0;j<4;j++){ int i = i0+j; if (i < NN) s += deg[i]; }
  #pragma unroll
  for (int off=32; off>=1; off>>=1) s += __shfl_xor(s, off, 64);
  if ((t&63)==0) ws[t>>6] = s;
  __syncthreads();
  if (t==0) bsum[b] = ws[0]+ws[1]+ws[2]+ws[3];
}

__global__ void k_scanb(const int* __restrict__ bsum, int* __restrict__ boff, int* __restrict__ rowptr){
  int lane = threadIdx.x;
  int v = (lane < NB) ? bsum[lane] : 0;
  int inc = v;
  #pragma unroll
  for (int off=1; off<64; off<<=1){ int u = __shfl_up(inc, off, 64); if (lane>=off) inc += u; }
  if (lane < NB) boff[lane] = inc - v;
  if (lane == 63) rowptr[NN] = inc;
}

__global__ void k_scanscatter(const int* __restrict__ deg, const int* __restrict__ boff,
                              int* __restrict__ rowptr, int* __restrict__ pos){
  __shared__ int ws[4];
  int t = threadIdx.x, b = blockIdx.x;
  int lane = t & 63, wid = t >> 6;
  int i0 = b*1024 + t*4;
  int d[4];
  #pragma unroll
  for (int j=0;j<4;j++){ int i=i0+j; d[j] = (i<NN)? deg[i] : 0; }
  int tot = d[0]+d[1]+d[2]+d[3];
  int inc = tot;
  #pragma unroll
  for (int off=1; off<64; off<<=1){ int u = __shfl_up(inc, off, 64); if (lane>=off) inc += u; }
  if (lane==63) ws[wid] = inc;
  __syncthreads();
  int woff = 0;
  for (int w=0; w<wid; w++) woff += ws[w];
  int base = boff[b] + woff + (inc - tot);
  int pre = 0;
  #pragma unroll
  for (int j=0;j<4;j++){
    int i = i0+j;
    if (i<NN){ rowptr[i] = base + pre; pos[i] = base + pre; }
    pre += d[j];
  }
}

__global__ void k_fill(const int* __restrict__ src, const int* __restrict__ dst,
                       int* __restrict__ pos, int* __restrict__ csr){
  int e = blockIdx.x*256 + threadIdx.x;
  if (e < EE){
    int d = dst[e];
    int p = atomicAdd(&pos[d], 1);
    csr[p] = src[e];
  }
}

// ---------------- weight prep: transpose + fp16 hi/lo split ------------------
__global__ void k_prep_w(const int* __restrict__ flags,
    const void* __restrict__ encW, const void* __restrict__ linW1,
    const void* __restrict__ W1, const void* __restrict__ W2,
    unsigned short* __restrict__ ph, unsigned short* __restrict__ pl)
{
  int idx = blockIdx.x*256 + threadIdx.x;   // grid covers 425984
  int fp32 = flags[0];
  const void* src; int off;
  if (idx < 16384){ int n=idx>>7, k=idx&127; src=encW; off=k*128+n; }
  else if (idx < 32768){ int o=idx-16384; int n=o>>7, k=o&127; src=linW1; off=k*128+n; }
  else if (idx < 229376){ int o=idx-32768; int l=o>>15, r=o&32767; int n=r>>7, k=r&127; src=W1; off=l*32768+k*256+n; }
  else { int o=idx-229376; int l=o>>15, r=o&32767; int n=r>>8, k=r&255; src=W2; off=l*32768+k*128+n; }
  float w = fp32 ? ((const float*)src)[off] : bf2f(((const unsigned short*)src)[off]);
  unsigned short h = f2h(w);
  ph[idx] = h;
  pl[idx] = f2h(w - h2f(h));
}

// small params -> fp32, concatenated
#define SM_ENCB 0
#define SM_LNG 128
#define SM_LNB 896
#define SM_TV 1664
#define SM_B1 1670
#define SM_MG 3206
#define SM_MB 4742
#define SM_B2 6278
#define SM_LINB1 7046
#define SM_LINW2 7174
#define SM_LINB2 7430
#define SM_TOT 7432
__global__ void k_prep_small(const int* __restrict__ flags,
    const void* s0, const void* s1, const void* s2, const void* s3,
    const void* s4, const void* s5, const void* s6, const void* s7,
    const void* s8, const void* s9, const void* s10, float* __restrict__ out)
{
  int i = blockIdx.x*256 + threadIdx.x;
  if (i >= SM_TOT) return;
  int fp32 = flags[0];
  const void* src; int off;
  if      (i < SM_LNG)  { src=s0;  off=i; }
  else if (i < SM_LNB)  { src=s1;  off=i-SM_LNG; }
  else if (i < SM_TV)   { src=s2;  off=i-SM_LNB; }
  else if (i < SM_B1)   { src=s3;  off=i-SM_TV; }
  else if (i < SM_MG)   { src=s4;  off=i-SM_B1; }
  else if (i < SM_MB)   { src=s5;  off=i-SM_MG; }
  else if (i < SM_B2)   { src=s6;  off=i-SM_MB; }
  else if (i < SM_LINB1){ src=s7;  off=i-SM_B2; }
  else if (i < SM_LINW2){ src=s8;  off=i-SM_LINB1; }
  else if (i < SM_LINB2){ src=s9;  off=i-SM_LINW2; }
  else                  { src=s10; off=i-SM_LINB2; }
  out[i] = fp32 ? ((const float*)src)[off] : bf2f(((const unsigned short*)src)[off]);
}

// me row: [m x128 | e' x128], e' = exp(min(m*t,18)-8); row NN = zeros (sink)
__device__ __forceinline__ void emit_me(unsigned short* me, int row, int col, float g, float tv){
  float m = g + 1e-7f;
  me[(size_t)row*256 + col] = f2h(m);
  me[(size_t)row*256 + 128 + col] = f2h(__expf(fminf(m*tv, 18.f) - 8.f));
}

// ---------------- generic f16 MFMA GEMM, K=128, tile 64x128 (enc + head) -----
// EPI: 0 = store fp32, 1 = relu+store fp32, 3 = store fp16.
template<int EPI>
__global__ __launch_bounds__(256, 4) void k_gemm(const void* __restrict__ Ap,
    const unsigned short* __restrict__ WTh, const unsigned short* __restrict__ WTl,
    const float* __restrict__ bias, void* __restrict__ Cv,
    int M, const int* __restrict__ flags, int aExt)
{
  __shared__ __align__(16) short lA[64*72];
  __shared__ __align__(16) short lW[128*72];

  const int tid = threadIdx.x, lane = tid & 63, wid = tid >> 6;
  const int mi = lane & 15, q = lane >> 4;
  const int rowb = blockIdx.x * 64;
  const int fp32m = flags[0];

  f32x4 acc[4][2];
  #pragma unroll
  for (int a=0;a<4;a++)
    #pragma unroll
    for (int c=0;c<2;c++){ acc[a][c][0]=0.f; acc[a][c][1]=0.f; acc[a][c][2]=0.f; acc[a][c][3]=0.f; }

  const int nW = fp32m ? 2 : 1;
  for (int pass = 0; pass < nW; ++pass){
    const unsigned short* Wp = pass ? WTl : WTh;
    for (int kc = 0; kc < 2; ++kc){
      {
        const int kv = (tid & 7) * 8, r0 = tid >> 3;
        #pragma unroll
        for (int p = 0; p < 2; ++p){
          int row = p*32 + r0, grow = rowb + row;
          uint4 d = make_uint4(0u,0u,0u,0u);
          if (grow < M){
            if (!aExt){
              d = *(const uint4*)((const unsigned short*)Ap + (size_t)grow*128 + kc*64 + kv);
            } else if (!fp32m){
              uint4 u = *(const uint4*)((const unsigned short*)Ap + (size_t)grow*128 + kc*64 + kv);
              const unsigned short* us = (const unsigned short*)&u;
              unsigned short hh[8];
              #pragma unroll
              for (int c=0;c<8;c++) hh[c] = f2h(bf2f(us[c]));
              d.x = hh[0]|((unsigned)hh[1]<<16); d.y = hh[2]|((unsigned)hh[3]<<16);
              d.z = hh[4]|((unsigned)hh[5]<<16); d.w = hh[6]|((unsigned)hh[7]<<16);
            } else {
              const float* fp = (const float*)Ap + (size_t)grow*128 + kc*64 + kv;
              float4 v0 = *(const float4*)fp, v1 = *(const float4*)(fp+4);
              unsigned short hh[8] = {f2h(v0.x),f2h(v0.y),f2h(v0.z),f2h(v0.w),
                                      f2h(v1.x),f2h(v1.y),f2h(v1.z),f2h(v1.w)};
              d.x = hh[0]|((unsigned)hh[1]<<16); d.y = hh[2]|((unsigned)hh[3]<<16);
              d.z = hh[4]|((unsigned)hh[5]<<16); d.w = hh[6]|((unsigned)hh[7]<<16);
            }
          }
          *(uint4*)&lA[row*72 + kv] = d;
        }
        #pragma unroll
        for (int p = 0; p < 4; ++p){
          int n = p*32 + r0;
          *(uint4*)&lW[n*72 + kv] = *(const uint4*)(Wp + (size_t)n*128 + kc*64 + kv);
        }
      }
      __syncthreads();
      #pragma unroll
      for (int ks = 0; ks < 2; ++ks){
        const int koff = ks*32 + q*8;
        f16x8 af[4], bw[2];
        #pragma unroll
        for (int rt=0; rt<4; rt++) af[rt] = *(const f16x8*)&lA[(rt*16+mi)*72 + koff];
        #pragma unroll
        for (int ct=0; ct<2; ct++) bw[ct] = *(const f16x8*)&lW[(wid*32 + ct*16 + mi)*72 + koff];
        #pragma unroll
        for (int rt=0; rt<4; rt++)
          #pragma unroll
          for (int ct=0; ct<2; ct++)
            acc[rt][ct] = __builtin_amdgcn_mfma_f32_16x16x32_f16(af[rt], bw[ct], acc[rt][ct], 0,0,0);
      }
      __syncthreads();
    }
  }
  #pragma unroll
  for (int ct=0; ct<2; ct++){
    const int col = wid*32 + ct*16 + mi;
    const float bf = bias[col];
    #pragma unroll
    for (int rt=0; rt<4; rt++)
      #pragma unroll
      for (int r=0; r<4; r++){
        int row = rowb + rt*16 + q*4 + r;
        if (row < M){
          float v = acc[rt][ct][r] + bf;
          if (EPI == 1) v = fmaxf(v, 0.f);
          if (EPI == 3) ((unsigned short*)Cv)[(size_t)row*128 + col] = f2h(v);
          else          ((float*)Cv)[(size_t)row*128 + col] = v;
        }
      }
  }
}

// ---------------- fused layer: z=relu(LN(A@W1+b1)) kept in LDS; -------------
// h16 += z@W2 + b2; optional next-layer preLN -> me. One kernel per layer.
// LDS union: stage1 lA[0,9216) + lW1[9216,46080); LN sred[0,2048);
//            stage2 zT[0,33792) + lW2[33792,52224); final h-LN sred[0,2048).
__global__ __launch_bounds__(256, 3) void k_layer(const unsigned short* __restrict__ Ap,
    const unsigned short* __restrict__ W1h, const unsigned short* __restrict__ W1l,
    const unsigned short* __restrict__ W2h, const unsigned short* __restrict__ W2l,
    const float* __restrict__ b1, const float* __restrict__ mg, const float* __restrict__ mb,
    const float* __restrict__ b2, unsigned short* __restrict__ h16,
    const float* __restrict__ gam, const float* __restrict__ bet,
    const float* __restrict__ tp, unsigned short* __restrict__ me,
    int M, const int* __restrict__ flags, int doLN)
{
  __shared__ __align__(16) char smem[52224];
  short* lA  = (short*)smem;             // 64 x 72
  short* lW1 = (short*)(smem + 9216);    // 256 x 72
  short* zT  = (short*)smem;             // 64 x 264
  short* lW2 = (short*)(smem + 33792);   // 128 x 72
  float2* sred = (float2*)smem;          // [4][64]

  const int tid = threadIdx.x, lane = tid & 63, wid = tid >> 6;
  const int mi = lane & 15, q = lane >> 4;
  const int kv = (tid & 7) * 8, r0 = tid >> 3;
  const int rowb = blockIdx.x * 64;
  const float tv = tp[0];
  const int nW = flags[0] ? 2 : 1;

  // ---- stage 1: z(64x256) = A(64x128) @ W1(128x256) + b1 ----
  f32x4 acc1[4][4];
  #pragma unroll
  for (int a=0;a<4;a++)
    #pragma unroll
    for (int c=0;c<4;c++){ acc1[a][c][0]=0.f; acc1[a][c][1]=0.f; acc1[a][c][2]=0.f; acc1[a][c][3]=0.f; }

  for (int pass = 0; pass < nW; ++pass){
    const unsigned short* Wp = pass ? W1l : W1h;
    for (int kc = 0; kc < 2; ++kc){
      if (pass == 0){
        #pragma unroll
        for (int p = 0; p < 2; ++p){
          int row = p*32 + r0, grow = rowb + row;
          uint4 d = make_uint4(0u,0u,0u,0u);
          if (grow < M) d = *(const uint4*)(Ap + (size_t)grow*128 + kc*64 + kv);
          *(uint4*)&lA[row*72 + kv] = d;
        }
      }
      #pragma unroll
      for (int p = 0; p < 8; ++p){
        int n = p*32 + r0;
        *(uint4*)&lW1[n*72 + kv] = *(const uint4*)(Wp + (size_t)n*128 + kc*64 + kv);
      }
      __syncthreads();
      #pragma unroll
      for (int ks = 0; ks < 2; ++ks){
        const int koff = ks*32 + q*8;
        f16x8 af[4], bw[4];
        #pragma unroll
        for (int rt=0; rt<4; rt++) af[rt] = *(const f16x8*)&lA[(rt*16+mi)*72 + koff];
        #pragma unroll
        for (int ct=0; ct<4; ct++) bw[ct] = *(const f16x8*)&lW1[(wid*64 + ct*16 + mi)*72 + koff];
        #pragma unroll
        for (int rt=0; rt<4; rt++)
          #pragma unroll
          for (int ct=0; ct<4; ct++)
            acc1[rt][ct] = __builtin_amdgcn_mfma_f32_16x16x32_f16(af[rt], bw[ct], acc1[rt][ct], 0,0,0);
      }
      __syncthreads();
    }
  }
  // + b1
  #pragma unroll
  for (int ct=0; ct<4; ct++){
    const float bf = b1[wid*64 + ct*16 + mi];
    #pragma unroll
    for (int rt=0; rt<4; rt++)
      #pragma unroll
      for (int r=0; r<4; r++) acc1[rt][ct][r] += bf;
  }
  // ---- LN over 256 cols (mln) ----
  #pragma unroll
  for (int rt=0; rt<4; rt++)
    #pragma unroll
    for (int r=0; r<4; r++){
      float s = 0.f, s2 = 0.f;
      #pragma unroll
      for (int ct=0; ct<4; ct++){ float v = acc1[rt][ct][r]; s += v; s2 += v*v; }
      #pragma unroll
      for (int off=1; off<16; off<<=1){ s += __shfl_xor(s, off, 64); s2 += __shfl_xor(s2, off, 64); }
      if (mi == 0) sred[wid*64 + rt*16 + q*4 + r] = make_float2(s, s2);
    }
  __syncthreads();
  float lnm[4][4], lnr[4][4];
  #pragma unroll
  for (int rt=0; rt<4; rt++)
    #pragma unroll
    for (int r=0; r<4; r++){
      int rl = rt*16 + q*4 + r;
      float2 t0 = sred[0*64+rl], t1 = sred[1*64+rl], t2 = sred[2*64+rl], t3 = sred[3*64+rl];
      float s = t0.x + t1.x + t2.x + t3.x;
      float s2 = t0.y + t1.y + t2.y + t3.y;
      float m = s * (1.f/256.f);
      float var = s2 * (1.f/256.f) - m*m;
      lnm[rt][r] = m;
      lnr[rt][r] = rsqrtf(var + 1e-5f);
    }
  __syncthreads();   // sred consumed; zT region may now be written
  // ---- write z tile into LDS (fp16, stride 264) ----
  #pragma unroll
  for (int ct=0; ct<4; ct++){
    const int col = wid*64 + ct*16 + mi;
    const float gc = mg[col], bc = mb[col];
    #pragma unroll
    for (int rt=0; rt<4; rt++)
      #pragma unroll
      for (int r=0; r<4; r++){
        int rl = rt*16 + q*4 + r;
        float v = (acc1[rt][ct][r] - lnm[rt][r]) * lnr[rt][r] * gc + bc;
        zT[rl*264 + col] = (short)f2h(fmaxf(v, 0.f));
      }
  }
  __syncthreads();
  // ---- stage 2: h(64x128) += z(64x256) @ W2(256x128) + b2 ----
  f32x4 acc2[4][2];
  #pragma unroll
  for (int a=0;a<4;a++)
    #pragma unroll
    for (int c=0;c<2;c++){ acc2[a][c][0]=0.f; acc2[a][c][1]=0.f; acc2[a][c][2]=0.f; acc2[a][c][3]=0.f; }

  for (int pass = 0; pass < nW; ++pass){
    const unsigned short* Wp = pass ? W2l : W2h;
    for (int kc = 0; kc < 4; ++kc){
      #pragma unroll
      for (int p = 0; p < 4; ++p){
        int n = p*32 + r0;
        *(uint4*)&lW2[n*72 + kv] = *(const uint4*)(Wp + (size_t)n*256 + kc*64 + kv);
      }
      __syncthreads();
      #pragma unroll
      for (int ks = 0; ks < 2; ++ks){
        const int koff = ks*32 + q*8;
        f16x8 af[4], bw[2];
        #pragma unroll
        for (int rt=0; rt<4; rt++) af[rt] = *(const f16x8*)&zT[(rt*16+mi)*264 + kc*64 + koff];
        #pragma unroll
        for (int ct=0; ct<2; ct++) bw[ct] = *(const f16x8*)&lW2[(wid*32 + ct*16 + mi)*72 + koff];
        #pragma unroll
        for (int rt=0; rt<4; rt++)
          #pragma unroll
          for (int ct=0; ct<2; ct++)
            acc2[rt][ct] = __builtin_amdgcn_mfma_f32_16x16x32_f16(af[rt], bw[ct], acc2[rt][ct], 0,0,0);
      }
      __syncthreads();
    }
  }
  // ---- residual + h16 writeback ----
  #pragma unroll
  for (int ct=0; ct<2; ct++){
    const int col = wid*32 + ct*16 + mi;
    const float bf = b2[col];
    #pragma unroll
    for (int rt=0; rt<4; rt++)
      #pragma unroll
      for (int r=0; r<4; r++){
        int row = rowb + rt*16 + q*4 + r;
        if (row < M){
          float hv = acc2[rt][ct][r] + bf + h2f(h16[(size_t)row*128 + col]);
          h16[(size_t)row*128 + col] = f2h(hv);
          acc2[rt][ct][r] = hv;
        }
      }
  }
  if (!doLN) return;
  // ---- next-layer preLN -> me ----
  #pragma unroll
  for (int rt=0; rt<4; rt++)
    #pragma unroll
    for (int r=0; r<4; r++){
      float s = 0.f, s2 = 0.f;
      #pragma unroll
      for (int ct=0; ct<2; ct++){ float v = acc2[rt][ct][r]; s += v; s2 += v*v; }
      #pragma unroll
      for (int off=1; off<16; off<<=1){ s += __shfl_xor(s, off, 64); s2 += __shfl_xor(s2, off, 64); }
      if (mi == 0) sred[wid*64 + rt*16 + q*4 + r] = make_float2(s, s2);
    }
  __syncthreads();
  #pragma unroll
  for (int rt=0; rt<4; rt++)
    #pragma unroll
    for (int r=0; r<4; r++){
      int rl = rt*16 + q*4 + r;
      float2 t0 = sred[0*64+rl], t1 = sred[1*64+rl], t2 = sred[2*64+rl], t3 = sred[3*64+rl];
      float s = t0.x + t1.x + t2.x + t3.x;
      float s2 = t0.y + t1.y + t2.y + t3.y;
      float m = s * (1.f/128.f);
      float var = s2 * (1.f/128.f) - m*m;
      float rs = rsqrtf(var + 1e-5f);
      int row = rowb + rl;
      if (row < M){
        #pragma unroll
        for (int ct=0; ct<2; ct++){
          int col = wid*32 + ct*16 + mi;
          float g = fmaxf((acc2[rt][ct][r] - m) * rs * gam[col] + bet[col], 0.f);
          emit_me(me, row, col, g, tv);
        }
      }
    }
}

// ---------------- layer-0 pre-LN (fp16 h) -> me table ------------------------
__global__ __launch_bounds__(256,4) void k_preln0(const unsigned short* __restrict__ h16,
    const float* __restrict__ gam, const float* __restrict__ bet,
    const float* __restrict__ tp, unsigned short* __restrict__ me)
{
  int wid = threadIdx.x >> 6, lane = threadIdx.x & 63;
  int row = blockIdx.x*4 + wid;
  float tv = tp[0];
  unsigned u = ((const unsigned*)(h16 + (size_t)row*DD))[lane];
  float v0 = h2f((unsigned short)(u & 0xffffu));
  float v1 = h2f((unsigned short)(u >> 16));
  float mean = wave_sum(v0+v1) * (1.f/128.f);
  float d0 = v0-mean, d1 = v1-mean;
  float var = wave_sum(d0*d0 + d1*d1) * (1.f/128.f);
  float rs = rsqrtf(var + 1e-5f);
  float o0 = fmaxf(d0*rs*gam[2*lane]   + bet[2*lane],   0.f);
  float o1 = fmaxf(d1*rs*gam[2*lane+1] + bet[2*lane+1], 0.f);
  emit_me(me, row, 2*lane,   o0, tv);
  emit_me(me, row, 2*lane+1, o1, tv);
}

// ---------------- softmax aggregation: 8 edges/iter, gather (m, e') ----------
__global__ __launch_bounds__(256,4) void k_agg(
    const unsigned short* __restrict__ me,
    const int* __restrict__ rowptr, const int* __restrict__ csr,
    unsigned short* __restrict__ obf)
{
  int wid = threadIdx.x>>6, lane = threadIdx.x&63;
  int node = blockIdx.x*4 + wid;
  int st = rowptr[node], en = rowptr[node+1];
  int quad = lane >> 4, fi = lane & 15;
  float l[8], ac[8];
  #pragma unroll
  for (int f=0; f<8; f++){ l[f]=0.f; ac[f]=0.f; }
  for (int base = st; base < en; base += 64){
    int cnt = min(64, en - base);
    int sv = (lane < cnt) ? csr[base + lane] : NN;   // NN = zero sink row
    for (int j = 0; j < cnt; j += 8){
      int s0i = __shfl(sv, j + quad, 64);
      int s1i = __shfl(sv, j + 4 + quad, 64);
      bool two = (j + 4) < cnt;
      const unsigned short* mer0 = me + (size_t)s0i*256 + fi*8;
      f16x8 mh0 = *(const f16x8*)(mer0);
      f16x8 eh0 = *(const f16x8*)(mer0 + 128);
      if (two){
        const unsigned short* mer1 = me + (size_t)s1i*256 + fi*8;
        f16x8 mh1 = *(const f16x8*)(mer1);
        f16x8 eh1 = *(const f16x8*)(mer1 + 128);
        #pragma unroll
        for (int f=0; f<8; f++){
          l[f]  = fmaf((float)eh0[f], 1.f, l[f]);
          ac[f] = fmaf((float)mh0[f], (float)eh0[f], ac[f]);
          l[f]  = fmaf((float)eh1[f], 1.f, l[f]);
          ac[f] = fmaf((float)mh1[f], (float)eh1[f], ac[f]);
        }
      } else {
        #pragma unroll
        for (int f=0; f<8; f++){
          l[f]  = fmaf((float)eh0[f], 1.f, l[f]);
          ac[f] = fmaf((float)mh0[f], (float)eh0[f], ac[f]);
        }
      }
    }
  }
  #pragma unroll
  for (int off=16; off<=32; off<<=1)
    #pragma unroll
    for (int f=0; f<8; f++){ l[f] += __shfl_xor(l[f], off, 64); ac[f] += __shfl_xor(ac[f], off, 64); }
  if (quad == 0){
    f16x8 mh = *(const f16x8*)(me + (size_t)node*256 + fi*8);
    unsigned short o[8];
    #pragma unroll
    for (int f=0; f<8; f++){
      float a = ac[f] / (l[f] + 1e-16f);
      o[f] = f2h(((float)mh[f] - 1e-7f) + a);
    }
    uint4 w;
    w.x = o[0]|((unsigned)o[1]<<16); w.y = o[2]|((unsigned)o[3]<<16);
    w.z = o[4]|((unsigned)o[5]<<16); w.w = o[6]|((unsigned)o[7]<<16);
    *(uint4*)(obf + (size_t)node*DD + fi*8) = w;
  }
}

// ---------------- head ----------------
__global__ __launch_bounds__(256,4) void k_head2(const float* __restrict__ u,
    const float* __restrict__ w, const float* __restrict__ b,
    void* __restrict__ out, const int* __restrict__ flags)
{
  int wid = threadIdx.x>>6, lane = threadIdx.x&63;
  int row = blockIdx.x*4 + wid;
  const float* ur = u + (size_t)row*DD;
  float u0 = ur[lane], u1 = ur[lane+64];
  float s0 = u0*w[lane*2+0] + u1*w[(lane+64)*2+0];
  float s1 = u0*w[lane*2+1] + u1*w[(lane+64)*2+1];
  s0 = wave_sum(s0); s1 = wave_sum(s1);
  if (lane == 0){
    float o0 = s0 + b[0], o1 = s1 + b[1];
    if (flags[0]){
      ((float*)out)[row*2+0] = o0;
      ((float*)out)[row*2+1] = o1;
    } else {
      ((unsigned short*)out)[row*2+0] = f2bf(o0);
      ((unsigned short*)out)[row*2+1] = f2bf(o1);
    }
  }
}

extern "C" void kernel_launch(void* const* d_in, const int* in_sizes, int n_in,
                              void* d_out, int out_size, void* d_ws, size_t ws_size,
                              hipStream_t stream)
{
  (void)in_sizes; (void)n_in; (void)out_size; (void)ws_size;
  char* ws = (char*)d_ws;
  size_t off = 0;
  auto alloc = [&](size_t bytes) -> char* {
    char* p = ws + off;
    off = (off + bytes + 255) & ~(size_t)255;
    return p;
  };
  int* flags  = (int*)alloc(256);
  float* sm   = (float*)alloc(SM_TOT*4);
  unsigned short* planeH = (unsigned short*)alloc(425984*2);
  unsigned short* planeL = (unsigned short*)alloc(425984*2);
  int* src32  = (int*)alloc((size_t)EE*4);
  int* dst32  = (int*)alloc((size_t)EE*4);
  int* deg    = (int*)alloc((size_t)NN*4);
  int* pos    = (int*)alloc((size_t)NN*4);
  int* rowptr = (int*)alloc((size_t)(NN+1)*4);
  int* csr    = (int*)alloc((size_t)EE*4);
  int* bsum   = (int*)alloc(64*4);
  int* boff   = (int*)alloc(64*4);
  unsigned short* h16 = (unsigned short*)alloc((size_t)NN*128*2);
  unsigned short* me   = (unsigned short*)alloc((size_t)(NN+1)*256*2);
  unsigned short* obf  = (unsigned short*)alloc((size_t)NN*128*2);
  float* ob   = (float*)alloc((size_t)NN*128*4);

  k_detect<<<1,256,0,stream>>>((const unsigned short*)d_in[0], (const unsigned int*)d_in[1], flags);
  k_cvt_edges<<<(EE+255)/256,256,0,stream>>>(d_in[1], flags, src32, dst32);
  hipMemsetAsync(deg, 0, (size_t)NN*4, stream);
  hipMemsetAsync(me + (size_t)NN*256, 0, 512, stream);   // zero sink row
  k_hist<<<(EE+255)/256,256,0,stream>>>(dst32, deg);
  k_blocksum<<<NB,256,0,stream>>>(deg, bsum);
  k_scanb<<<1,64,0,stream>>>(bsum, boff, rowptr);
  k_scanscatter<<<NB,256,0,stream>>>(deg, boff, rowptr, pos);
  k_fill<<<(EE+255)/256,256,0,stream>>>(src32, dst32, pos, csr);
  k_prep_w<<<1664,256,0,stream>>>(flags, d_in[2], d_in[13], d_in[7], d_in[11], planeH, planeL);
  k_prep_small<<<30,256,0,stream>>>(flags, d_in[3], d_in[4], d_in[5], d_in[6], d_in[8],
                                    d_in[9], d_in[10], d_in[12], d_in[14], d_in[15], d_in[16], sm);

  const int GB = (NN + 63)/64;  // 782
  // encoder: h16 = fp16(x @ enc_W + enc_b)
  k_gemm<3><<<GB,256,0,stream>>>((const void*)d_in[0], planeH + 0, planeL + 0,
                                 sm + SM_ENCB, (void*)h16, NN, flags, 1);
  k_preln0<<<NN/4,256,0,stream>>>(h16, sm + SM_LNG, sm + SM_LNB, sm + SM_TV, me);
  for (int i = 0; i < LL; ++i){
    k_agg<<<NN/4,256,0,stream>>>(me, rowptr, csr, obf);
    int nl = (i+1 < LL) ? (i+1) : 0;
    k_layer<<<GB,256,0,stream>>>(obf,
                                 planeH + 32768 + i*32768, planeL + 32768 + i*32768,
                                 planeH + 229376 + i*32768, planeL + 229376 + i*32768,
                                 sm + SM_B1 + i*256, sm + SM_MG + i*256, sm + SM_MB + i*256,
                                 sm + SM_B2 + i*128, h16,
                                 sm + SM_LNG + nl*128, sm + SM_LNB + nl*128,
                                 sm + SM_TV + nl,
                                 me, NN, flags, (i+1 < LL) ? 1 : 0);
  }
  // head: ob = relu(h16 @ lin_W1 + lin_b1)
  k_gemm<1><<<GB,256,0,stream>>>((const void*)h16, planeH + 16384, planeL + 16384,
                                 sm + SM_LINB1, (void*)ob, NN, flags, 0);
  k_head2<<<NN/4,256,0,stream>>>(ob, sm + SM_LINW2, sm + SM_LINB2, d_out, flags);
}

// Round 9
// 807.871 us; speedup vs baseline: 1.1100x; 1.0940x over previous
//
#include <hip/hip_runtime.h>

#define NN 50000
#define EE 600000
#define DD 128
#define HH 256
#define LL 6
#define NB 49   // ceil(NN/1024)

typedef _Float16 f16x8 __attribute__((ext_vector_type(8)));
typedef float f32x4 __attribute__((ext_vector_type(4)));

__device__ __forceinline__ float bf2f(unsigned short u){
  unsigned int x = ((unsigned int)u) << 16; float f; __builtin_memcpy(&f, &x, 4); return f;
}
__device__ __forceinline__ unsigned short f2bf(float f){
  unsigned int x; __builtin_memcpy(&x, &f, 4);
  unsigned int lsb = (x >> 16) & 1u; x += 0x7fffu + lsb; return (unsigned short)(x >> 16);
}
__device__ __forceinline__ float wave_sum(float v){
  #pragma unroll
  for (int off = 32; off >= 1; off >>= 1) v += __shfl_xor(v, off, 64);
  return v;
}
__device__ __forceinline__ unsigned short f2h(float f){
  _Float16 h = (_Float16)f; unsigned short u; __builtin_memcpy(&u, &h, 2); return u;
}
__device__ __forceinline__ float h2f(unsigned short u){
  _Float16 h; __builtin_memcpy(&h, &u, 2); return (float)h;
}

// ---------------- dtype detection (device-side, capture-safe) ----------------
__global__ void k_detect(const unsigned short* __restrict__ xh,
                         const unsigned int* __restrict__ ew,
                         int* __restrict__ flags){
  __shared__ int s_bad, s_nz;
  int t = threadIdx.x;
  if (t == 0){ s_bad = 0; s_nz = 0; }
  __syncthreads();
  int bad = 0;
  for (int i = t; i < 512; i += 256){
    unsigned e = (xh[i] >> 7) & 0xffu;
    if (e < 96u || e > 135u) bad = 1;
  }
  if (bad) atomicOr(&s_bad, 1);
  int nz = 0;
  for (int i = t; i < 1024; i += 256)
    if ((i & 1) && ew[i] != 0u) nz = 1;
  if (nz) atomicOr(&s_nz, 1);
  __syncthreads();
  if (t == 0){
    flags[0] = s_bad ? 1 : 0;
    flags[1] = s_nz ? 0 : 1;
  }
}

__global__ void k_cvt_edges(const void* __restrict__ ei, const int* __restrict__ flags,
                            int* __restrict__ s32, int* __restrict__ d32){
  int e = blockIdx.x*256 + threadIdx.x;
  if (e >= EE) return;
  int sv, dv;
  if (flags[1]){
    const long long* p = (const long long*)ei;
    sv = (int)p[e]; dv = (int)p[EE + e];
  } else {
    const int* p = (const int*)ei;
    sv = p[e]; dv = p[EE + e];
  }
  s32[e] = ((unsigned)sv < (unsigned)NN) ? sv : 0;
  d32[e] = ((unsigned)dv < (unsigned)NN) ? dv : 0;
}

// ---------------- CSR build ----------------
__global__ void k_hist(const int* __restrict__ dst, int* __restrict__ deg){
  int e = blockIdx.x*256 + threadIdx.x;
  if (e < EE) atomicAdd(&deg[dst[e]], 1);
}

__global__ void k_blocksum(const int* __restrict__ deg, int* __restrict__ bsum){
  __shared__ int ws[4];
  int t = threadIdx.x, b = blockIdx.x;
  int s = 0;
  int i0 = b*1024 + t*4;
  #pragma unroll
  for (int j=0;j<4;j++){ int i = i0+j; if (i < NN) s += deg[i]; }
  #pragma unroll
  for (int off=32; off>=1; off>>=1) s += __shfl_xor(s, off, 64);
  if ((t&63)==0) ws[t>>6] = s;
  __syncthreads();
  if (t==0) bsum[b] = ws[0]+ws[1]+ws[2]+ws[3];
}

__global__ void k_scanb(const int* __restrict__ bsum, int* __restrict__ boff, int* __restrict__ rowptr){
  int lane = threadIdx.x;
  int v = (lane < NB) ? bsum[lane] : 0;
  int inc = v;
  #pragma unroll
  for (int off=1; off<64; off<<=1){ int u = __shfl_up(inc, off, 64); if (lane>=off) inc += u; }
  if (lane < NB) boff[lane] = inc - v;
  if (lane == 63) rowptr[NN] = inc;
}

__global__ void k_scanscatter(const int* __restrict__ deg, const int* __restrict__ boff,
                              int* __restrict__ rowptr, int* __restrict__ pos){
  __shared__ int ws[4];
  int t = threadIdx.x, b = blockIdx.x;
  int lane = t & 63, wid = t >> 6;
  int i0 = b*1024 + t*4;
  int d[4];
  #pragma unroll
  for (int j=0;j<4;j++){ int i=i0+j; d[j] = (i<NN)? deg[i] : 0; }
  int tot = d[0]+d[1]+d[2]+d[3];
  int inc = tot;
  #pragma unroll
  for (int off=1; off<64; off<<=1){ int u = __shfl_up(inc, off, 64); if (lane>=off) inc += u; }
  if (lane==63) ws[wid] = inc;
  __syncthreads();
  int woff = 0;
  for (int w=0; w<wid; w++) woff += ws[w];
  int base = boff[b] + woff + (inc - tot);
  int pre = 0;
  #pragma unroll
  for (int j=0;j<4;j++){
    int i = i0+j;
    if (i<NN){ rowptr[i] = base + pre; pos[i] = base + pre; }
    pre += d[j];
  }
}

__global__ void k_fill(const int* __restrict__ src, const int* __restrict__ dst,
                       int* __restrict__ pos, int* __restrict__ csr){
  int e = blockIdx.x*256 + threadIdx.x;
  if (e < EE){
    int d = dst[e];
    int p = atomicAdd(&pos[d], 1);
    csr[p] = src[e];
  }
}

// ---------------- weight prep: transpose + fp16 hi/lo split ------------------
__global__ void k_prep_w(const int* __restrict__ flags,
    const void* __restrict__ encW, const void* __restrict__ linW1,
    const void* __restrict__ W1, const void* __restrict__ W2,
    unsigned short* __restrict__ ph, unsigned short* __restrict__ pl)
{
  int idx = blockIdx.x*256 + threadIdx.x;   // grid covers 425984
  int fp32 = flags[0];
  const void* src; int off;
  if (idx < 16384){ int n=idx>>7, k=idx&127; src=encW; off=k*128+n; }
  else if (idx < 32768){ int o=idx-16384; int n=o>>7, k=o&127; src=linW1; off=k*128+n; }
  else if (idx < 229376){ int o=idx-32768; int l=o>>15, r=o&32767; int n=r>>7, k=r&127; src=W1; off=l*32768+k*256+n; }
  else { int o=idx-229376; int l=o>>15, r=o&32767; int n=r>>8, k=r&255; src=W2; off=l*32768+k*128+n; }
  float w = fp32 ? ((const float*)src)[off] : bf2f(((const unsigned short*)src)[off]);
  unsigned short h = f2h(w);
  ph[idx] = h;
  pl[idx] = f2h(w - h2f(h));
}

// small params -> fp32, concatenated
#define SM_ENCB 0
#define SM_LNG 128
#define SM_LNB 896
#define SM_TV 1664
#define SM_B1 1670
#define SM_MG 3206
#define SM_MB 4742
#define SM_B2 6278
#define SM_LINB1 7046
#define SM_LINW2 7174
#define SM_LINB2 7430
#define SM_TOT 7432
__global__ void k_prep_small(const int* __restrict__ flags,
    const void* s0, const void* s1, const void* s2, const void* s3,
    const void* s4, const void* s5, const void* s6, const void* s7,
    const void* s8, const void* s9, const void* s10, float* __restrict__ out)
{
  int i = blockIdx.x*256 + threadIdx.x;
  if (i >= SM_TOT) return;
  int fp32 = flags[0];
  const void* src; int off;
  if      (i < SM_LNG)  { src=s0;  off=i; }
  else if (i < SM_LNB)  { src=s1;  off=i-SM_LNG; }
  else if (i < SM_TV)   { src=s2;  off=i-SM_LNB; }
  else if (i < SM_B1)   { src=s3;  off=i-SM_TV; }
  else if (i < SM_MG)   { src=s4;  off=i-SM_B1; }
  else if (i < SM_MB)   { src=s5;  off=i-SM_MG; }
  else if (i < SM_B2)   { src=s6;  off=i-SM_MB; }
  else if (i < SM_LINB1){ src=s7;  off=i-SM_B2; }
  else if (i < SM_LINW2){ src=s8;  off=i-SM_LINB1; }
  else if (i < SM_LINB2){ src=s9;  off=i-SM_LINW2; }
  else                  { src=s10; off=i-SM_LINB2; }
  out[i] = fp32 ? ((const float*)src)[off] : bf2f(((const unsigned short*)src)[off]);
}

// me row: [m x128 | e' x128], e' = exp(min(m*t,18)-8); row NN = zeros (sink)
__device__ __forceinline__ void emit_me(unsigned short* me, int row, int col, float g, float tv){
  float m = g + 1e-7f;
  me[(size_t)row*256 + col] = f2h(m);
  me[(size_t)row*256 + 128 + col] = f2h(__expf(fminf(m*tv, 18.f) - 8.f));
}

// ---------------- generic f16 MFMA GEMM, K=128, tile 64x128 (enc + head) -----
// EPI: 0 = store fp32, 1 = relu+store fp32, 3 = store fp16 (LDS-coalesced).
template<int EPI>
__global__ __launch_bounds__(256, 4) void k_gemm(const void* __restrict__ Ap,
    const unsigned short* __restrict__ WTh, const unsigned short* __restrict__ WTl,
    const float* __restrict__ bias, void* __restrict__ Cv,
    int M, const int* __restrict__ flags, int aExt)
{
  __shared__ __align__(16) char smem[27648];
  short* lA = (short*)smem;            // 64 x 72
  short* lW = (short*)(smem + 9216);   // 128 x 72
  short* hT = (short*)smem;            // 64 x 136 (epilogue overlay)

  const int tid = threadIdx.x, lane = tid & 63, wid = tid >> 6;
  const int mi = lane & 15, q = lane >> 4;
  const int rowb = blockIdx.x * 64;
  const int fp32m = flags[0];

  f32x4 acc[4][2];
  #pragma unroll
  for (int a=0;a<4;a++)
    #pragma unroll
    for (int c=0;c<2;c++){ acc[a][c][0]=0.f; acc[a][c][1]=0.f; acc[a][c][2]=0.f; acc[a][c][3]=0.f; }

  const int nW = fp32m ? 2 : 1;
  for (int pass = 0; pass < nW; ++pass){
    const unsigned short* Wp = pass ? WTl : WTh;
    for (int kc = 0; kc < 2; ++kc){
      {
        const int kv = (tid & 7) * 8, r0 = tid >> 3;
        #pragma unroll
        for (int p = 0; p < 2; ++p){
          int row = p*32 + r0, grow = rowb + row;
          uint4 d = make_uint4(0u,0u,0u,0u);
          if (grow < M){
            if (!aExt){
              d = *(const uint4*)((const unsigned short*)Ap + (size_t)grow*128 + kc*64 + kv);
            } else if (!fp32m){
              uint4 u = *(const uint4*)((const unsigned short*)Ap + (size_t)grow*128 + kc*64 + kv);
              const unsigned short* us = (const unsigned short*)&u;
              unsigned short hh[8];
              #pragma unroll
              for (int c=0;c<8;c++) hh[c] = f2h(bf2f(us[c]));
              d.x = hh[0]|((unsigned)hh[1]<<16); d.y = hh[2]|((unsigned)hh[3]<<16);
              d.z = hh[4]|((unsigned)hh[5]<<16); d.w = hh[6]|((unsigned)hh[7]<<16);
            } else {
              const float* fp = (const float*)Ap + (size_t)grow*128 + kc*64 + kv;
              float4 v0 = *(const float4*)fp, v1 = *(const float4*)(fp+4);
              unsigned short hh[8] = {f2h(v0.x),f2h(v0.y),f2h(v0.z),f2h(v0.w),
                                      f2h(v1.x),f2h(v1.y),f2h(v1.z),f2h(v1.w)};
              d.x = hh[0]|((unsigned)hh[1]<<16); d.y = hh[2]|((unsigned)hh[3]<<16);
              d.z = hh[4]|((unsigned)hh[5]<<16); d.w = hh[6]|((unsigned)hh[7]<<16);
            }
          }
          *(uint4*)&lA[row*72 + kv] = d;
        }
        #pragma unroll
        for (int p = 0; p < 4; ++p){
          int n = p*32 + (tid >> 3);
          *(uint4*)&lW[n*72 + (tid & 7)*8] = *(const uint4*)(Wp + (size_t)n*128 + kc*64 + (tid & 7)*8);
        }
      }
      __syncthreads();
      #pragma unroll
      for (int ks = 0; ks < 2; ++ks){
        const int koff = ks*32 + q*8;
        f16x8 af[4], bw[2];
        #pragma unroll
        for (int rt=0; rt<4; rt++) af[rt] = *(const f16x8*)&lA[(rt*16+mi)*72 + koff];
        #pragma unroll
        for (int ct=0; ct<2; ct++) bw[ct] = *(const f16x8*)&lW[(wid*32 + ct*16 + mi)*72 + koff];
        #pragma unroll
        for (int rt=0; rt<4; rt++)
          #pragma unroll
          for (int ct=0; ct<2; ct++)
            acc[rt][ct] = __builtin_amdgcn_mfma_f32_16x16x32_f16(af[rt], bw[ct], acc[rt][ct], 0,0,0);
      }
      __syncthreads();
    }
  }
  if (EPI == 3){
    // stage into LDS, then coalesced uint4 stores
    #pragma unroll
    for (int ct=0; ct<2; ct++){
      const int col = wid*32 + ct*16 + mi;
      const float bf = bias[col];
      #pragma unroll
      for (int rt=0; rt<4; rt++)
        #pragma unroll
        for (int r=0; r<4; r++)
          hT[(rt*16 + q*4 + r)*136 + col] = (short)f2h(acc[rt][ct][r] + bf);
    }
    __syncthreads();
    unsigned short* C16 = (unsigned short*)Cv;
    #pragma unroll
    for (int i = 0; i < 4; ++i){
      int idx = i*256 + tid;
      int prow = idx >> 4, pl = idx & 15;
      int grow = rowb + prow;
      if (grow < M)
        *(uint4*)(C16 + (size_t)grow*128 + pl*8) = *(const uint4*)&hT[prow*136 + pl*8];
    }
  } else {
    #pragma unroll
    for (int ct=0; ct<2; ct++){
      const int col = wid*32 + ct*16 + mi;
      const float bf = bias[col];
      #pragma unroll
      for (int rt=0; rt<4; rt++)
        #pragma unroll
        for (int r=0; r<4; r++){
          int row = rowb + rt*16 + q*4 + r;
          if (row < M){
            float v = acc[rt][ct][r] + bf;
            if (EPI == 1) v = fmaxf(v, 0.f);
            ((float*)Cv)[(size_t)row*128 + col] = v;
          }
        }
    }
  }
}

// ---------------- fused layer: z=relu(LN(A@W1+b1)) in LDS; ------------------
// h16 += z@W2 + b2 (prefetched, coalesced); preLN -> me via LDS-coalesced I/O.
// LDS plan (53248 B): stage1 lA[0,9216)+lW1[9216,46080);
//   zT[0,33792)+lW2[33792,52224); epi: hT[0,17408)+mE[17408,51200); sred[51200,53248)
__global__ __launch_bounds__(256, 3) void k_layer(const unsigned short* __restrict__ Ap,
    const unsigned short* __restrict__ W1h, const unsigned short* __restrict__ W1l,
    const unsigned short* __restrict__ W2h, const unsigned short* __restrict__ W2l,
    const float* __restrict__ b1, const float* __restrict__ mg, const float* __restrict__ mb,
    const float* __restrict__ b2, unsigned short* __restrict__ h16,
    const float* __restrict__ gam, const float* __restrict__ bet,
    const float* __restrict__ tp, unsigned short* __restrict__ me,
    int M, const int* __restrict__ flags, int doLN)
{
  __shared__ __align__(16) char smem[53248];
  short* lA  = (short*)smem;             // 64 x 72
  short* lW1 = (short*)(smem + 9216);    // 256 x 72
  short* zT  = (short*)smem;             // 64 x 264
  short* lW2 = (short*)(smem + 33792);   // 128 x 72
  short* hT  = (short*)smem;             // 64 x 136 (epilogue)
  short* mE  = (short*)(smem + 17408);   // 64 x 264 (epilogue)
  float2* sred = (float2*)(smem + 51200);

  const int tid = threadIdx.x, lane = tid & 63, wid = tid >> 6;
  const int mi = lane & 15, q = lane >> 4;
  const int kv = (tid & 7) * 8, r0 = tid >> 3;
  const int rowb = blockIdx.x * 64;
  const float tv = tp[0];
  const int nW = flags[0] ? 2 : 1;
  const int prow = tid >> 4;               // prefetch/store mapping: 4 iters of 16 rows
  const int pl = tid & 15;

  // ---- stage 1: z(64x256) = A(64x128) @ W1(128x256) + b1 ----
  f32x4 acc1[4][4];
  #pragma unroll
  for (int a=0;a<4;a++)
    #pragma unroll
    for (int c=0;c<4;c++){ acc1[a][c][0]=0.f; acc1[a][c][1]=0.f; acc1[a][c][2]=0.f; acc1[a][c][3]=0.f; }

  for (int pass = 0; pass < nW; ++pass){
    const unsigned short* Wp = pass ? W1l : W1h;
    for (int kc = 0; kc < 2; ++kc){
      if (pass == 0){
        #pragma unroll
        for (int p = 0; p < 2; ++p){
          int row = p*32 + r0, grow = rowb + row;
          uint4 d = make_uint4(0u,0u,0u,0u);
          if (grow < M) d = *(const uint4*)(Ap + (size_t)grow*128 + kc*64 + kv);
          *(uint4*)&lA[row*72 + kv] = d;
        }
      }
      #pragma unroll
      for (int p = 0; p < 8; ++p){
        int n = p*32 + r0;
        *(uint4*)&lW1[n*72 + kv] = *(const uint4*)(Wp + (size_t)n*128 + kc*64 + kv);
      }
      __syncthreads();
      #pragma unroll
      for (int ks = 0; ks < 2; ++ks){
        const int koff = ks*32 + q*8;
        f16x8 af[4], bw[4];
        #pragma unroll
        for (int rt=0; rt<4; rt++) af[rt] = *(const f16x8*)&lA[(rt*16+mi)*72 + koff];
        #pragma unroll
        for (int ct=0; ct<4; ct++) bw[ct] = *(const f16x8*)&lW1[(wid*64 + ct*16 + mi)*72 + koff];
        #pragma unroll
        for (int rt=0; rt<4; rt++)
          #pragma unroll
          for (int ct=0; ct<4; ct++)
            acc1[rt][ct] = __builtin_amdgcn_mfma_f32_16x16x32_f16(af[rt], bw[ct], acc1[rt][ct], 0,0,0);
      }
      __syncthreads();
    }
  }
  // + b1, LN(256) stats
  #pragma unroll
  for (int ct=0; ct<4; ct++){
    const float bf = b1[wid*64 + ct*16 + mi];
    #pragma unroll
    for (int rt=0; rt<4; rt++)
      #pragma unroll
      for (int r=0; r<4; r++) acc1[rt][ct][r] += bf;
  }
  #pragma unroll
  for (int rt=0; rt<4; rt++)
    #pragma unroll
    for (int r=0; r<4; r++){
      float s = 0.f, s2 = 0.f;
      #pragma unroll
      for (int ct=0; ct<4; ct++){ float v = acc1[rt][ct][r]; s += v; s2 += v*v; }
      #pragma unroll
      for (int off=1; off<16; off<<=1){ s += __shfl_xor(s, off, 64); s2 += __shfl_xor(s2, off, 64); }
      if (mi == 0) sred[wid*64 + rt*16 + q*4 + r] = make_float2(s, s2);
    }
  __syncthreads();
  float lnm[4][4], lnr[4][4];
  #pragma unroll
  for (int rt=0; rt<4; rt++)
    #pragma unroll
    for (int r=0; r<4; r++){
      int rl = rt*16 + q*4 + r;
      float2 t0 = sred[0*64+rl], t1 = sred[1*64+rl], t2 = sred[2*64+rl], t3 = sred[3*64+rl];
      float s = t0.x + t1.x + t2.x + t3.x;
      float s2 = t0.y + t1.y + t2.y + t3.y;
      float m = s * (1.f/256.f);
      float var = s2 * (1.f/256.f) - m*m;
      lnm[rt][r] = m;
      lnr[rt][r] = rsqrtf(var + 1e-5f);
    }
  __syncthreads();
  // ---- park z tile in LDS (fp16, stride 264) ----
  #pragma unroll
  for (int ct=0; ct<4; ct++){
    const int col = wid*64 + ct*16 + mi;
    const float gc = mg[col], bc = mb[col];
    #pragma unroll
    for (int rt=0; rt<4; rt++)
      #pragma unroll
      for (int r=0; r<4; r++){
        int rl = rt*16 + q*4 + r;
        float v = (acc1[rt][ct][r] - lnm[rt][r]) * lnr[rt][r] * gc + bc;
        zT[rl*264 + col] = (short)f2h(fmaxf(v, 0.f));
      }
  }
  __syncthreads();
  // ---- prefetch old h tile (coalesced; latency hidden behind stage 2) ----
  uint4 hpre[4];
  #pragma unroll
  for (int i = 0; i < 4; ++i){
    int grow = rowb + i*16 + prow;
    hpre[i] = make_uint4(0u,0u,0u,0u);
    if (grow < M) hpre[i] = *(const uint4*)(h16 + (size_t)grow*128 + pl*8);
  }
  // ---- stage 2: h(64x128) += z(64x256) @ W2(256x128) + b2 ----
  f32x4 acc2[4][2];
  #pragma unroll
  for (int a=0;a<4;a++)
    #pragma unroll
    for (int c=0;c<2;c++){ acc2[a][c][0]=0.f; acc2[a][c][1]=0.f; acc2[a][c][2]=0.f; acc2[a][c][3]=0.f; }

  for (int pass = 0; pass < nW; ++pass){
    const unsigned short* Wp = pass ? W2l : W2h;
    for (int kc = 0; kc < 4; ++kc){
      #pragma unroll
      for (int p = 0; p < 4; ++p){
        int n = p*32 + r0;
        *(uint4*)&lW2[n*72 + kv] = *(const uint4*)(Wp + (size_t)n*256 + kc*64 + kv);
      }
      __syncthreads();
      #pragma unroll
      for (int ks = 0; ks < 2; ++ks){
        const int koff = ks*32 + q*8;
        f16x8 af[4], bw[2];
        #pragma unroll
        for (int rt=0; rt<4; rt++) af[rt] = *(const f16x8*)&zT[(rt*16+mi)*264 + kc*64 + koff];
        #pragma unroll
        for (int ct=0; ct<2; ct++) bw[ct] = *(const f16x8*)&lW2[(wid*32 + ct*16 + mi)*72 + koff];
        #pragma unroll
        for (int rt=0; rt<4; rt++)
          #pragma unroll
          for (int ct=0; ct<2; ct++)
            acc2[rt][ct] = __builtin_amdgcn_mfma_f32_16x16x32_f16(af[rt], bw[ct], acc2[rt][ct], 0,0,0);
      }
      __syncthreads();
    }
  }
  // ---- epilogue: LDS-staged, coalesced I/O ----
  // 1. park old h in LDS
  #pragma unroll
  for (int i = 0; i < 4; ++i)
    *(uint4*)&hT[(i*16 + prow)*136 + pl*8] = hpre[i];
  __syncthreads();
  // 2. residual add in register layout; hnew -> same LDS slots
  #pragma unroll
  for (int ct=0; ct<2; ct++){
    const int col = wid*32 + ct*16 + mi;
    const float bf = b2[col];
    #pragma unroll
    for (int rt=0; rt<4; rt++)
      #pragma unroll
      for (int r=0; r<4; r++){
        int rl = rt*16 + q*4 + r;
        float hv = acc2[rt][ct][r] + bf + h2f((unsigned short)hT[rl*136 + col]);
        hT[rl*136 + col] = (short)f2h(hv);
        acc2[rt][ct][r] = hv;
      }
  }
  if (doLN){
    // 3. LN stats over 128 cols
    #pragma unroll
    for (int rt=0; rt<4; rt++)
      #pragma unroll
      for (int r=0; r<4; r++){
        float s = 0.f, s2 = 0.f;
        #pragma unroll
        for (int ct=0; ct<2; ct++){ float v = acc2[rt][ct][r]; s += v; s2 += v*v; }
        #pragma unroll
        for (int off=1; off<16; off<<=1){ s += __shfl_xor(s, off, 64); s2 += __shfl_xor(s2, off, 64); }
        if (mi == 0) sred[wid*64 + rt*16 + q*4 + r] = make_float2(s, s2);
      }
    __syncthreads();
    #pragma unroll
    for (int rt=0; rt<4; rt++)
      #pragma unroll
      for (int r=0; r<4; r++){
        int rl = rt*16 + q*4 + r;
        float2 t0 = sred[0*64+rl], t1 = sred[1*64+rl], t2 = sred[2*64+rl], t3 = sred[3*64+rl];
        float s = t0.x + t1.x + t2.x + t3.x;
        float s2 = t0.y + t1.y + t2.y + t3.y;
        float m = s * (1.f/128.f);
        float var = s2 * (1.f/128.f) - m*m;
        float rs = rsqrtf(var + 1e-5f);
        #pragma unroll
        for (int ct=0; ct<2; ct++){
          int col = wid*32 + ct*16 + mi;
          float g = fmaxf((acc2[rt][ct][r] - m) * rs * gam[col] + bet[col], 0.f);
          float mm = g + 1e-7f;
          mE[rl*264 + col] = (short)f2h(mm);
          mE[rl*264 + 128 + col] = (short)f2h(__expf(fminf(mm*tv, 18.f) - 8.f));
        }
      }
  }
  __syncthreads();
  // 4. coalesced global stores
  #pragma unroll
  for (int i = 0; i < 4; ++i){
    int grow = rowb + i*16 + prow;
    if (grow < M)
      *(uint4*)(h16 + (size_t)grow*128 + pl*8) = *(const uint4*)&hT[(i*16 + prow)*136 + pl*8];
  }
  if (doLN){
    #pragma unroll
    for (int i = 0; i < 8; ++i){
      int idx2 = i*256 + tid;            // [0,2048)
      int mrow = idx2 >> 5, part = (idx2 >> 4) & 1, l16 = idx2 & 15;
      int grow = rowb + mrow;
      if (grow < M)
        *(uint4*)(me + (size_t)grow*256 + part*128 + l16*8)
          = *(const uint4*)&mE[mrow*264 + part*128 + l16*8];
    }
  }
}

// ---------------- layer-0 pre-LN (fp16 h) -> me table ------------------------
__global__ __launch_bounds__(256,4) void k_preln0(const unsigned short* __restrict__ h16,
    const float* __restrict__ gam, const float* __restrict__ bet,
    const float* __restrict__ tp, unsigned short* __restrict__ me)
{
  int wid = threadIdx.x >> 6, lane = threadIdx.x & 63;
  int row = blockIdx.x*4 + wid;
  float tv = tp[0];
  unsigned u = ((const unsigned*)(h16 + (size_t)row*DD))[lane];
  float v0 = h2f((unsigned short)(u & 0xffffu));
  float v1 = h2f((unsigned short)(u >> 16));
  float mean = wave_sum(v0+v1) * (1.f/128.f);
  float d0 = v0-mean, d1 = v1-mean;
  float var = wave_sum(d0*d0 + d1*d1) * (1.f/128.f);
  float rs = rsqrtf(var + 1e-5f);
  float o0 = fmaxf(d0*rs*gam[2*lane]   + bet[2*lane],   0.f);
  float o1 = fmaxf(d1*rs*gam[2*lane+1] + bet[2*lane+1], 0.f);
  emit_me(me, row, 2*lane,   o0, tv);
  emit_me(me, row, 2*lane+1, o1, tv);
}

// ---------------- softmax aggregation: 8 edges/iter, gather (m, e') ----------
__global__ __launch_bounds__(256,4) void k_agg(
    const unsigned short* __restrict__ me,
    const int* __restrict__ rowptr, const int* __restrict__ csr,
    unsigned short* __restrict__ obf)
{
  int wid = threadIdx.x>>6, lane = threadIdx.x&63;
  int node = blockIdx.x*4 + wid;
  int st = rowptr[node], en = rowptr[node+1];
  int quad = lane >> 4, fi = lane & 15;
  float l[8], ac[8];
  #pragma unroll
  for (int f=0; f<8; f++){ l[f]=0.f; ac[f]=0.f; }
  for (int base = st; base < en; base += 64){
    int cnt = min(64, en - base);
    int sv = (lane < cnt) ? csr[base + lane] : NN;   // NN = zero sink row
    for (int j = 0; j < cnt; j += 8){
      int s0i = __shfl(sv, j + quad, 64);
      int s1i = __shfl(sv, j + 4 + quad, 64);
      bool two = (j + 4) < cnt;
      const unsigned short* mer0 = me + (size_t)s0i*256 + fi*8;
      f16x8 mh0 = *(const f16x8*)(mer0);
      f16x8 eh0 = *(const f16x8*)(mer0 + 128);
      if (two){
        const unsigned short* mer1 = me + (size_t)s1i*256 + fi*8;
        f16x8 mh1 = *(const f16x8*)(mer1);
        f16x8 eh1 = *(const f16x8*)(mer1 + 128);
        #pragma unroll
        for (int f=0; f<8; f++){
          l[f]  = fmaf((float)eh0[f], 1.f, l[f]);
          ac[f] = fmaf((float)mh0[f], (float)eh0[f], ac[f]);
          l[f]  = fmaf((float)eh1[f], 1.f, l[f]);
          ac[f] = fmaf((float)mh1[f], (float)eh1[f], ac[f]);
        }
      } else {
        #pragma unroll
        for (int f=0; f<8; f++){
          l[f]  = fmaf((float)eh0[f], 1.f, l[f]);
          ac[f] = fmaf((float)mh0[f], (float)eh0[f], ac[f]);
        }
      }
    }
  }
  #pragma unroll
  for (int off=16; off<=32; off<<=1)
    #pragma unroll
    for (int f=0; f<8; f++){ l[f] += __shfl_xor(l[f], off, 64); ac[f] += __shfl_xor(ac[f], off, 64); }
  if (quad == 0){
    f16x8 mh = *(const f16x8*)(me + (size_t)node*256 + fi*8);
    unsigned short o[8];
    #pragma unroll
    for (int f=0; f<8; f++){
      float a = ac[f] / (l[f] + 1e-16f);
      o[f] = f2h(((float)mh[f] - 1e-7f) + a);
    }
    uint4 w;
    w.x = o[0]|((unsigned)o[1]<<16); w.y = o[2]|((unsigned)o[3]<<16);
    w.z = o[4]|((unsigned)o[5]<<16); w.w = o[6]|((unsigned)o[7]<<16);
    *(uint4*)(obf + (size_t)node*DD + fi*8) = w;
  }
}

// ---------------- head ----------------
__global__ __launch_bounds__(256,4) void k_head2(const float* __restrict__ u,
    const float* __restrict__ w, const float* __restrict__ b,
    void* __restrict__ out, const int* __restrict__ flags)
{
  int wid = threadIdx.x>>6, lane = threadIdx.x&63;
  int row = blockIdx.x*4 + wid;
  const float* ur = u + (size_t)row*DD;
  float u0 = ur[lane], u1 = ur[lane+64];
  float s0 = u0*w[lane*2+0] + u1*w[(lane+64)*2+0];
  float s1 = u0*w[lane*2+1] + u1*w[(lane+64)*2+1];
  s0 = wave_sum(s0); s1 = wave_sum(s1);
  if (lane == 0){
    float o0 = s0 + b[0], o1 = s1 + b[1];
    if (flags[0]){
      ((float*)out)[row*2+0] = o0;
      ((float*)out)[row*2+1] = o1;
    } else {
      ((unsigned short*)out)[row*2+0] = f2bf(o0);
      ((unsigned short*)out)[row*2+1] = f2bf(o1);
    }
  }
}

extern "C" void kernel_launch(void* const* d_in, const int* in_sizes, int n_in,
                              void* d_out, int out_size, void* d_ws, size_t ws_size,
                              hipStream_t stream)
{
  (void)in_sizes; (void)n_in; (void)out_size; (void)ws_size;
  char* ws = (char*)d_ws;
  size_t off = 0;
  auto alloc = [&](size_t bytes) -> char* {
    char* p = ws + off;
    off = (off + bytes + 255) & ~(size_t)255;
    return p;
  };
  int* flags  = (int*)alloc(256);
  float* sm   = (float*)alloc(SM_TOT*4);
  unsigned short* planeH = (unsigned short*)alloc(425984*2);
  unsigned short* planeL = (unsigned short*)alloc(425984*2);
  int* src32  = (int*)alloc((size_t)EE*4);
  int* dst32  = (int*)alloc((size_t)EE*4);
  int* deg    = (int*)alloc((size_t)NN*4);
  int* pos    = (int*)alloc((size_t)NN*4);
  int* rowptr = (int*)alloc((size_t)(NN+1)*4);
  int* csr    = (int*)alloc((size_t)EE*4);
  int* bsum   = (int*)alloc(64*4);
  int* boff   = (int*)alloc(64*4);
  unsigned short* h16 = (unsigned short*)alloc((size_t)NN*128*2);
  unsigned short* me   = (unsigned short*)alloc((size_t)(NN+1)*256*2);
  unsigned short* obf  = (unsigned short*)alloc((size_t)NN*128*2);
  float* ob   = (float*)alloc((size_t)NN*128*4);

  k_detect<<<1,256,0,stream>>>((const unsigned short*)d_in[0], (const unsigned int*)d_in[1], flags);
  k_cvt_edges<<<(EE+255)/256,256,0,stream>>>(d_in[1], flags, src32, dst32);
  hipMemsetAsync(deg, 0, (size_t)NN*4, stream);
  hipMemsetAsync(me + (size_t)NN*256, 0, 512, stream);   // zero sink row
  k_hist<<<(EE+255)/256,256,0,stream>>>(dst32, deg);
  k_blocksum<<<NB,256,0,stream>>>(deg, bsum);
  k_scanb<<<1,64,0,stream>>>(bsum, boff, rowptr);
  k_scanscatter<<<NB,256,0,stream>>>(deg, boff, rowptr, pos);
  k_fill<<<(EE+255)/256,256,0,stream>>>(src32, dst32, pos, csr);
  k_prep_w<<<1664,256,0,stream>>>(flags, d_in[2], d_in[13], d_in[7], d_in[11], planeH, planeL);
  k_prep_small<<<30,256,0,stream>>>(flags, d_in[3], d_in[4], d_in[5], d_in[6], d_in[8],
                                    d_in[9], d_in[10], d_in[12], d_in[14], d_in[15], d_in[16], sm);

  const int GB = (NN + 63)/64;  // 782
  // encoder: h16 = fp16(x @ enc_W + enc_b)
  k_gemm<3><<<GB,256,0,stream>>>((const void*)d_in[0], planeH + 0, planeL + 0,
                                 sm + SM_ENCB, (void*)h16, NN, flags, 1);
  k_preln0<<<NN/4,256,0,stream>>>(h16, sm + SM_LNG, sm + SM_LNB, sm + SM_TV, me);
  for (int i = 0; i < LL; ++i){
    k_agg<<<NN/4,256,0,stream>>>(me, rowptr, csr, obf);
    int nl = (i+1 < LL) ? (i+1) : 0;
    k_layer<<<GB,256,0,stream>>>(obf,
                                 planeH + 32768 + i*32768, planeL + 32768 + i*32768,
                                 planeH + 229376 + i*32768, planeL + 229376 + i*32768,
                                 sm + SM_B1 + i*256, sm + SM_MG + i*256, sm + SM_MB + i*256,
                                 sm + SM_B2 + i*128, h16,
                                 sm + SM_LNG + nl*128, sm + SM_LNB + nl*128,
                                 sm + SM_TV + nl,
                                 me, NN, flags, (i+1 < LL) ? 1 : 0);
  }
  // head: ob = relu(h16 @ lin_W1 + lin_b1)
  k_gemm<1><<<GB,256,0,stream>>>((const void*)h16, planeH + 16384, planeL + 16384,
                                 sm + SM_LINB1, (void*)ob, NN, flags, 0);
  k_head2<<<NN/4,256,0,stream>>>(ob, sm + SM_LINW2, sm + SM_LINB2, d_out, flags);
}